// Round 2
// baseline (356.758 us; speedup 1.0000x reference)
//
#include <hip/hip_runtime.h>
#include <hip/hip_bf16.h>
#include <stdint.h>
#include <stddef.h>

typedef __hip_bfloat16 bf16;
typedef short bf16x8 __attribute__((ext_vector_type(8)));
typedef float f32x4 __attribute__((ext_vector_type(4)));

// Problem constants
#define BB 2
#define SS 2048
#define DM 2048
#define NH 32
#define NG 8
#define DH 64
#define ROWS (BB * SS)   // 4096
#define NQK 2560         // Q cols (2048) + K cols (512)

__device__ __forceinline__ void gload_lds16(const void* g, void* l) {
  __builtin_amdgcn_global_load_lds((const __attribute__((address_space(1))) void*)g,
                                   (__attribute__((address_space(3))) void*)l, 16, 0, 0);
}

// ---------------- f32 -> bf16 convert, 4 elements/thread ----------------
__global__ __launch_bounds__(256) void cvt_f32_bf16(const float* __restrict__ in,
                                                    bf16* __restrict__ out, int n4) {
  int i = blockIdx.x * 256 + threadIdx.x;
  if (i >= n4) return;
  float4 v = reinterpret_cast<const float4*>(in)[i];
  bf16 t0 = __float2bfloat16(v.x), t1 = __float2bfloat16(v.y);
  bf16 t2 = __float2bfloat16(v.z), t3 = __float2bfloat16(v.w);
  ushort4 o;
  o.x = *reinterpret_cast<unsigned short*>(&t0);
  o.y = *reinterpret_cast<unsigned short*>(&t1);
  o.z = *reinterpret_cast<unsigned short*>(&t2);
  o.w = *reinterpret_cast<unsigned short*>(&t3);
  reinterpret_cast<ushort4*>(out)[i] = o;
}

// ---------------- GEMM: C[M][N] = A[M][K] * B[N][K]^T (bf16 in, CT out) ----
__device__ __forceinline__ void store_elem(float* C, size_t i, float v) { C[i] = v; }
__device__ __forceinline__ void store_elem(bf16* C, size_t i, float v) { C[i] = __float2bfloat16(v); }

template <typename CT>
__global__ __launch_bounds__(256) void gemm_bt(const bf16* __restrict__ A,
                                               const bf16* __restrict__ Bm,
                                               CT* __restrict__ C,
                                               int M, int N, int K) {
  const int t = threadIdx.x;
  const int w = t >> 6, lane = t & 63, lg = lane >> 4, lr = lane & 15;
  const int wr = w >> 1, wc = w & 1;
  const int rowA = blockIdx.y * 128, rowB = blockIdx.x * 128;
  __shared__ __align__(16) bf16 sA[128 * 32];
  __shared__ __align__(16) bf16 sB[128 * 32];
  f32x4 acc[4][4] = {};
  for (int k0 = 0; k0 < K; k0 += 32) {
    // stage 128x32 A-tile and B-tile: LDS linear, XOR-swizzled global source
#pragma unroll
    for (int i = 0; i < 2; ++i) {
      const int c = i * 256 + t;           // 16B chunk index, 4 chunks/row
      const int r = c >> 2, slot = c & 3;
      const int ck = slot ^ ((r >> 1) & 3);
      gload_lds16(A + (size_t)(rowA + r) * K + k0 + ck * 8, &sA[c * 8]);
      gload_lds16(Bm + (size_t)(rowB + r) * K + k0 + ck * 8, &sB[c * 8]);
    }
    asm volatile("s_waitcnt vmcnt(0)" ::: "memory");
    __syncthreads();
    bf16x8 af[4], bfv[4];
#pragma unroll
    for (int mi = 0; mi < 4; ++mi) {
      const int r = wr * 64 + mi * 16 + lr;
      af[mi] = *(const bf16x8*)&sA[r * 32 + (lg ^ ((r >> 1) & 3)) * 8];
    }
#pragma unroll
    for (int ni = 0; ni < 4; ++ni) {
      const int r = wc * 64 + ni * 16 + lr;
      bfv[ni] = *(const bf16x8*)&sB[r * 32 + (lg ^ ((r >> 1) & 3)) * 8];
    }
#pragma unroll
    for (int mi = 0; mi < 4; ++mi)
#pragma unroll
      for (int ni = 0; ni < 4; ++ni)
        acc[mi][ni] = __builtin_amdgcn_mfma_f32_16x16x32_bf16(af[mi], bfv[ni], acc[mi][ni], 0, 0, 0);
    __syncthreads();
  }
  // epilogue: C/D layout col = lane&15, row = 4*(lane>>4)+reg
#pragma unroll
  for (int mi = 0; mi < 4; ++mi)
#pragma unroll
    for (int ni = 0; ni < 4; ++ni) {
      const int row0 = rowA + wr * 64 + mi * 16 + 4 * lg;
      const int col = rowB + wc * 64 + ni * 16 + lr;
#pragma unroll
      for (int r = 0; r < 4; ++r)
        store_elem(C, (size_t)(row0 + r) * N + col, acc[mi][ni][r]);
    }
}

// ---------------- fused GQA flash attention ----------------
// qk: [4096][2560] bf16 (Q cols 0..2047 = h*64+d, K cols 2048+g*64+d)
// vt: [512][4096] bf16 (row = g*64+d, col = b*2048+s)
// ctx: [4096][2048] bf16 out
__global__ __launch_bounds__(256) void gqa_attn(const bf16* __restrict__ qk,
                                                const bf16* __restrict__ vt,
                                                bf16* __restrict__ ctx) {
  const int t = threadIdx.x, w = t >> 6, lane = t & 63, lg = lane >> 4, lr = lane & 15;
  const int head = blockIdx.y, b = head >> 5, h = head & 31, g = h >> 2;
  const int qb = blockIdx.x * 64;
  const size_t LD = NQK;
  const bf16* Qp = qk + (size_t)b * SS * LD + h * 64;
  const bf16* Kp = qk + (size_t)b * SS * LD + 2048 + g * 64;
  const bf16* Vt = vt + (size_t)(g * 64) * ROWS + b * SS;

  __shared__ __align__(16) bf16 sK[64 * 64];         // [key][d], slot-swizzled
  __shared__ __align__(16) bf16 sV[64 * 64];         // [d][key], slot-swizzled
  __shared__ __align__(16) bf16 sP[4][16 * 72];      // per-wave P, stride 72

  // Q A-fragments (rows = wave's 16 q-rows; lane row = lr, k = 8*lg+j)
  bf16x8 qf[2];
  {
    const bf16* qrow = Qp + (size_t)(qb + w * 16 + lr) * LD;
    qf[0] = *(const bf16x8*)(qrow + lg * 8);
    qf[1] = *(const bf16x8*)(qrow + 32 + lg * 8);
  }

  float m_run[4], l_run[4];
  f32x4 o[4];
#pragma unroll
  for (int r = 0; r < 4; ++r) { m_run[r] = -3.0e38f; l_run[r] = 0.0f; }
#pragma unroll
  for (int dg = 0; dg < 4; ++dg) o[dg] = (f32x4){0.f, 0.f, 0.f, 0.f};

  for (int kt = 0; kt < SS / 64; ++kt) {
    // stage K tile [64 keys][64 d] and V^T tile [64 d][64 keys]
#pragma unroll
    for (int i = 0; i < 2; ++i) {
      const int c = i * 256 + t;           // 16B chunk, 8 chunks/row
      const int r = c >> 3, slot = c & 7;
      const int ck = slot ^ (r & 7);
      gload_lds16(Kp + (size_t)(kt * 64 + r) * LD + ck * 8, &sK[c * 8]);
      gload_lds16(Vt + (size_t)r * ROWS + kt * 64 + ck * 8, &sV[c * 8]);
    }
    asm volatile("s_waitcnt vmcnt(0)" ::: "memory");
    __syncthreads();

    // S = Q K^T  (s[cg][reg] = S[4*lg+reg][cg*16+lr])
    f32x4 s[4];
#pragma unroll
    for (int cg = 0; cg < 4; ++cg) {
      const int kr = cg * 16 + lr;
      bf16x8 kf0 = *(const bf16x8*)&sK[kr * 64 + ((lg) ^ (kr & 7)) * 8];
      bf16x8 kf1 = *(const bf16x8*)&sK[kr * 64 + ((lg + 4) ^ (kr & 7)) * 8];
      f32x4 z = {0.f, 0.f, 0.f, 0.f};
      z = __builtin_amdgcn_mfma_f32_16x16x32_bf16(qf[0], kf0, z, 0, 0, 0);
      z = __builtin_amdgcn_mfma_f32_16x16x32_bf16(qf[1], kf1, z, 0, 0, 0);
      s[cg] = z;
    }
#pragma unroll
    for (int cg = 0; cg < 4; ++cg) s[cg] *= 0.125f;  // 1/sqrt(64)

    // online softmax per q-row
#pragma unroll
    for (int r = 0; r < 4; ++r) {
      float m = fmaxf(fmaxf(s[0][r], s[1][r]), fmaxf(s[2][r], s[3][r]));
      m = fmaxf(m, __shfl_xor(m, 1));
      m = fmaxf(m, __shfl_xor(m, 2));
      m = fmaxf(m, __shfl_xor(m, 4));
      m = fmaxf(m, __shfl_xor(m, 8));
      const float mn = fmaxf(m_run[r], m);
      const float corr = __expf(m_run[r] - mn);
      m_run[r] = mn;
      l_run[r] *= corr;
#pragma unroll
      for (int dg = 0; dg < 4; ++dg) o[dg][r] *= corr;
    }
    // P = exp(s - m), accumulate per-lane partial l, park P in wave-private LDS
    bf16* sPw = sP[w];
#pragma unroll
    for (int cg = 0; cg < 4; ++cg)
#pragma unroll
      for (int r = 0; r < 4; ++r) {
        float p = __expf(s[cg][r] - m_run[r]);
        l_run[r] += p;
        sPw[(4 * lg + r) * 72 + cg * 16 + lr] = __float2bfloat16(p);
      }

    // O += P @ V  (A = P [16 q][64 keys], B = V [64 keys][16 d])
#pragma unroll
    for (int kc = 0; kc < 2; ++kc) {
      bf16x8 pf = *(const bf16x8*)&sPw[lr * 72 + kc * 32 + lg * 8];
#pragma unroll
      for (int dg = 0; dg < 4; ++dg) {
        const int vr = dg * 16 + lr;
        bf16x8 vf = *(const bf16x8*)&sV[vr * 64 + ((kc * 4 + lg) ^ (vr & 7)) * 8];
        o[dg] = __builtin_amdgcn_mfma_f32_16x16x32_bf16(pf, vf, o[dg], 0, 0, 0);
      }
    }
    __syncthreads();
  }

  // FIX (round 1): l_run per lane held only its 4 columns' partial sums —
  // reduce the softmax denominator across the 16-lane lr-group before dividing.
  // (m_run is shfl-max-reduced every tile, so partials share a consistent scale.)
#pragma unroll
  for (int r = 0; r < 4; ++r) {
    float l = l_run[r];
    l += __shfl_xor(l, 1);
    l += __shfl_xor(l, 2);
    l += __shfl_xor(l, 4);
    l += __shfl_xor(l, 8);
    l_run[r] = l;
  }

  // normalize + write ctx (row = b*2048 + q, col = h*64 + d)
  const int orow0 = b * SS + qb + w * 16 + 4 * lg;
#pragma unroll
  for (int dg = 0; dg < 4; ++dg) {
    const int col = h * 64 + dg * 16 + lr;
#pragma unroll
    for (int r = 0; r < 4; ++r) {
      float v = o[dg][r] / l_run[r];
      ctx[(size_t)(orow0 + r) * DM + col] = __float2bfloat16(v);
    }
  }
}

// ---------------- launch ----------------
extern "C" void kernel_launch(void* const* d_in, const int* in_sizes, int n_in,
                              void* d_out, int out_size, void* d_ws, size_t ws_size,
                              hipStream_t stream) {
  const float* x   = (const float*)d_in[0];
  const float* W_q = (const float*)d_in[1];
  const float* W_k = (const float*)d_in[2];
  const float* W_v = (const float*)d_in[3];
  const float* W_o = (const float*)d_in[4];
  float* out = (float*)d_out;

  char* ws = (char*)d_ws;
  bf16* xb    = (bf16*)ws; ws += (size_t)ROWS * DM * 2;     // 16.8 MB
  bf16* wqk   = (bf16*)ws; ws += (size_t)NQK * DM * 2;      // 10.5 MB
  bf16* wv    = (bf16*)ws; ws += (size_t)(NG * DH) * DM * 2; // 2.1 MB
  bf16* wo    = (bf16*)ws; ws += (size_t)DM * DM * 2;       // 8.4 MB
  bf16* qkbuf = (bf16*)ws; ws += (size_t)ROWS * NQK * 2;    // 21.0 MB
  bf16* vtb   = (bf16*)ws; ws += (size_t)(NG * DH) * ROWS * 2; // 4.2 MB
  bf16* ctx   = (bf16*)ws; ws += (size_t)ROWS * DM * 2;     // 16.8 MB

  // converts
  {
    int n4;
    n4 = (ROWS * DM) / 4;
    cvt_f32_bf16<<<n4 / 256, 256, 0, stream>>>(x, xb, n4);
    n4 = (2048 * DM) / 4;
    cvt_f32_bf16<<<n4 / 256, 256, 0, stream>>>(W_q, wqk, n4);
    n4 = (512 * DM) / 4;
    cvt_f32_bf16<<<n4 / 256, 256, 0, stream>>>(W_k, wqk + (size_t)2048 * DM, n4);
    cvt_f32_bf16<<<n4 / 256, 256, 0, stream>>>(W_v, wv, n4);
    n4 = (DM * DM) / 4;
    cvt_f32_bf16<<<n4 / 256, 256, 0, stream>>>(W_o, wo, n4);
  }

  // QK projection: qkbuf[4096][2560] = xb @ wqk^T
  gemm_bt<bf16><<<dim3(NQK / 128, ROWS / 128), 256, 0, stream>>>(xb, wqk, qkbuf, ROWS, NQK, DM);
  // V projection, transposed: vtb[512][4096] = wv @ xb^T
  gemm_bt<bf16><<<dim3(ROWS / 128, (NG * DH) / 128), 256, 0, stream>>>(wv, xb, vtb, NG * DH, ROWS, DM);
  // attention
  gqa_attn<<<dim3(SS / 64, BB * NH), 256, 0, stream>>>(qkbuf, vtb, ctx);
  // output projection: out[4096][2048] f32 = ctx @ wo^T
  gemm_bt<float><<<dim3(DM / 128, ROWS / 128), 256, 0, stream>>>(ctx, wo, out, ROWS, DM, DM);
}

// Round 3
// 327.011 us; speedup vs baseline: 1.0910x; 1.0910x over previous
//
#include <hip/hip_runtime.h>
#include <hip/hip_bf16.h>
#include <stdint.h>
#include <stddef.h>

typedef __hip_bfloat16 bf16;
typedef short bf16x8 __attribute__((ext_vector_type(8)));
typedef float f32x4 __attribute__((ext_vector_type(4)));

// Problem constants
#define BB 2
#define SS 2048
#define DM 2048
#define NH 32
#define NG 8
#define DH 64
#define ROWS (BB * SS)   // 4096
#define NQK 2560         // Q cols (2048) + K cols (512)

// sqrt(0.125 * log2(e)) — applied to BOTH Q and K columns in the QK-proj GEMM,
// so S = (aQ)(aK)^T arrives pre-scaled for exp2-domain softmax.
#define ALPHA_QK 0.4246609001440095f

__device__ __forceinline__ void gload_lds16(const void* g, void* l) {
  __builtin_amdgcn_global_load_lds((const __attribute__((address_space(1))) void*)g,
                                   (__attribute__((address_space(3))) void*)l, 16, 0, 0);
}

// ---------------- f32 -> bf16 convert, 4 elements/thread ----------------
__global__ __launch_bounds__(256) void cvt_f32_bf16(const float* __restrict__ in,
                                                    bf16* __restrict__ out, int n4) {
  int i = blockIdx.x * 256 + threadIdx.x;
  if (i >= n4) return;
  float4 v = reinterpret_cast<const float4*>(in)[i];
  bf16 t0 = __float2bfloat16(v.x), t1 = __float2bfloat16(v.y);
  bf16 t2 = __float2bfloat16(v.z), t3 = __float2bfloat16(v.w);
  ushort4 o;
  o.x = *reinterpret_cast<unsigned short*>(&t0);
  o.y = *reinterpret_cast<unsigned short*>(&t1);
  o.z = *reinterpret_cast<unsigned short*>(&t2);
  o.w = *reinterpret_cast<unsigned short*>(&t3);
  reinterpret_cast<ushort4*>(out)[i] = o;
}

// ---------------- GEMM: C[M][N] = alpha * A[M][K] * B[N][K]^T ----
__device__ __forceinline__ void store_elem(float* C, size_t i, float v) { C[i] = v; }
__device__ __forceinline__ void store_elem(bf16* C, size_t i, float v) { C[i] = __float2bfloat16(v); }

template <typename CT>
__global__ __launch_bounds__(256) void gemm_bt(const bf16* __restrict__ A,
                                               const bf16* __restrict__ Bm,
                                               CT* __restrict__ C,
                                               int M, int N, int K, float alpha) {
  const int t = threadIdx.x;
  const int w = t >> 6, lane = t & 63, lg = lane >> 4, lr = lane & 15;
  const int wr = w >> 1, wc = w & 1;
  const int rowA = blockIdx.y * 128, rowB = blockIdx.x * 128;
  __shared__ __align__(16) bf16 sA[128 * 32];
  __shared__ __align__(16) bf16 sB[128 * 32];
  f32x4 acc[4][4] = {};
  for (int k0 = 0; k0 < K; k0 += 32) {
#pragma unroll
    for (int i = 0; i < 2; ++i) {
      const int c = i * 256 + t;           // 16B chunk index, 4 chunks/row
      const int r = c >> 2, slot = c & 3;
      const int ck = slot ^ ((r >> 1) & 3);
      gload_lds16(A + (size_t)(rowA + r) * K + k0 + ck * 8, &sA[c * 8]);
      gload_lds16(Bm + (size_t)(rowB + r) * K + k0 + ck * 8, &sB[c * 8]);
    }
    asm volatile("s_waitcnt vmcnt(0)" ::: "memory");
    __syncthreads();
    bf16x8 af[4], bfv[4];
#pragma unroll
    for (int mi = 0; mi < 4; ++mi) {
      const int r = wr * 64 + mi * 16 + lr;
      af[mi] = *(const bf16x8*)&sA[r * 32 + (lg ^ ((r >> 1) & 3)) * 8];
    }
#pragma unroll
    for (int ni = 0; ni < 4; ++ni) {
      const int r = wc * 64 + ni * 16 + lr;
      bfv[ni] = *(const bf16x8*)&sB[r * 32 + (lg ^ ((r >> 1) & 3)) * 8];
    }
#pragma unroll
    for (int mi = 0; mi < 4; ++mi)
#pragma unroll
      for (int ni = 0; ni < 4; ++ni)
        acc[mi][ni] = __builtin_amdgcn_mfma_f32_16x16x32_bf16(af[mi], bfv[ni], acc[mi][ni], 0, 0, 0);
    __syncthreads();
  }
#pragma unroll
  for (int mi = 0; mi < 4; ++mi)
#pragma unroll
    for (int ni = 0; ni < 4; ++ni) {
      const int row0 = rowA + wr * 64 + mi * 16 + 4 * lg;
      const int col = rowB + wc * 64 + ni * 16 + lr;
#pragma unroll
      for (int r = 0; r < 4; ++r)
        store_elem(C, (size_t)(row0 + r) * N + col, acc[mi][ni][r] * alpha);
    }
}

// ---------------- fused GQA flash attention ----------------
// qk: [4096][2560] bf16, PRE-SCALED by sqrt(0.125*log2e) on both Q and K parts.
// vt: [512][4096] bf16 (row = g*64+d, col = b*2048+s)
// ctx: [4096][2048] bf16 out
__global__ __launch_bounds__(256) void gqa_attn(const bf16* __restrict__ qk,
                                                const bf16* __restrict__ vt,
                                                bf16* __restrict__ ctx) {
  const int t = threadIdx.x, w = t >> 6, lane = t & 63, lg = lane >> 4, lr = lane & 15;
  const int head = blockIdx.y, b = head >> 5, h = head & 31, g = h >> 2;
  const int qb = blockIdx.x * 64;
  const size_t LD = NQK;
  const bf16* Qp = qk + (size_t)b * SS * LD + h * 64;
  const bf16* Kp = qk + (size_t)b * SS * LD + 2048 + g * 64;
  const bf16* Vt = vt + (size_t)(g * 64) * ROWS + b * SS;

  __shared__ __align__(16) bf16 sK[2][64 * 64];      // [key][d], slot-swizzled, dbuf
  __shared__ __align__(16) bf16 sV[2][64 * 64];      // [d][key], slot-swizzled, dbuf
  __shared__ __align__(16) bf16 sP[4][16 * 72];      // per-wave P, stride 72

  bf16x8 qf[2];
  {
    const bf16* qrow = Qp + (size_t)(qb + w * 16 + lr) * LD;
    qf[0] = *(const bf16x8*)(qrow + lg * 8);
    qf[1] = *(const bf16x8*)(qrow + 32 + lg * 8);
  }

  float m_run[4], l_run[4];
  f32x4 o[4];
#pragma unroll
  for (int r = 0; r < 4; ++r) { m_run[r] = -3.0e38f; l_run[r] = 0.0f; }
#pragma unroll
  for (int dg = 0; dg < 4; ++dg) o[dg] = (f32x4){0.f, 0.f, 0.f, 0.f};

  auto STAGE = [&](int bi, int kt) {
#pragma unroll
    for (int i = 0; i < 2; ++i) {
      const int c = i * 256 + t;           // 16B chunk, 8 chunks/row
      const int r = c >> 3, slot = c & 7;
      const int ck = slot ^ (r & 7);
      gload_lds16(Kp + (size_t)(kt * 64 + r) * LD + ck * 8, &sK[bi][c * 8]);
      gload_lds16(Vt + (size_t)r * ROWS + kt * 64 + ck * 8, &sV[bi][c * 8]);
    }
  };

  STAGE(0, 0);
  __syncthreads();   // drains vmcnt -> tile 0 resident
  int cur = 0;

  for (int kt = 0; kt < SS / 64; ++kt) {
    // T3-minimum: issue next tile's loads BEFORE computing current tile
    if (kt + 1 < SS / 64) STAGE(cur ^ 1, kt + 1);

    // S = Q K^T  (s[cg][reg] = S[4*lg+reg][cg*16+lr]); already exp2-scaled
    f32x4 s[4];
#pragma unroll
    for (int cg = 0; cg < 4; ++cg) {
      const int kr = cg * 16 + lr;
      bf16x8 kf0 = *(const bf16x8*)&sK[cur][kr * 64 + ((lg) ^ (kr & 7)) * 8];
      bf16x8 kf1 = *(const bf16x8*)&sK[cur][kr * 64 + ((lg + 4) ^ (kr & 7)) * 8];
      f32x4 z = {0.f, 0.f, 0.f, 0.f};
      z = __builtin_amdgcn_mfma_f32_16x16x32_bf16(qf[0], kf0, z, 0, 0, 0);
      z = __builtin_amdgcn_mfma_f32_16x16x32_bf16(qf[1], kf1, z, 0, 0, 0);
      s[cg] = z;
    }

    // T13 defer-max: lane-local per-row max; full reduce+rescale only if needed
    float pm[4];
#pragma unroll
    for (int r = 0; r < 4; ++r)
      pm[r] = fmaxf(fmaxf(s[0][r], s[1][r]), fmaxf(s[2][r], s[3][r]));
    const bool ok = (pm[0] <= m_run[0] + 8.f) && (pm[1] <= m_run[1] + 8.f) &&
                    (pm[2] <= m_run[2] + 8.f) && (pm[3] <= m_run[3] + 8.f);
    if (!__all(ok)) {
#pragma unroll
      for (int r = 0; r < 4; ++r) {
        float m = pm[r];
        m = fmaxf(m, __shfl_xor(m, 1));
        m = fmaxf(m, __shfl_xor(m, 2));
        m = fmaxf(m, __shfl_xor(m, 4));
        m = fmaxf(m, __shfl_xor(m, 8));
        const float mn = fmaxf(m_run[r], m);
        const float corr = __builtin_amdgcn_exp2f(m_run[r] - mn);
        m_run[r] = mn;
        l_run[r] *= corr;
#pragma unroll
        for (int dg = 0; dg < 4; ++dg) o[dg][r] *= corr;
      }
    }

    // P = exp2(s - m) (bounded by 2^8 under defer), park in wave-private LDS
    bf16* sPw = sP[w];
#pragma unroll
    for (int cg = 0; cg < 4; ++cg)
#pragma unroll
      for (int r = 0; r < 4; ++r) {
        float p = __builtin_amdgcn_exp2f(s[cg][r] - m_run[r]);
        l_run[r] += p;
        sPw[(4 * lg + r) * 72 + cg * 16 + lr] = __float2bfloat16(p);
      }

    // O += P @ V
#pragma unroll
    for (int kc = 0; kc < 2; ++kc) {
      bf16x8 pf = *(const bf16x8*)&sPw[lr * 72 + kc * 32 + lg * 8];
#pragma unroll
      for (int dg = 0; dg < 4; ++dg) {
        const int vr = dg * 16 + lr;
        bf16x8 vf = *(const bf16x8*)&sV[cur][vr * 64 + ((kc * 4 + lg) ^ (vr & 7)) * 8];
        o[dg] = __builtin_amdgcn_mfma_f32_16x16x32_bf16(pf, vf, o[dg], 0, 0, 0);
      }
    }
    __syncthreads();   // drains vmcnt (next tile resident) + all waves done with cur
    cur ^= 1;
  }

  // reduce softmax denominator across the 16-lane lr-group
#pragma unroll
  for (int r = 0; r < 4; ++r) {
    float l = l_run[r];
    l += __shfl_xor(l, 1);
    l += __shfl_xor(l, 2);
    l += __shfl_xor(l, 4);
    l += __shfl_xor(l, 8);
    l_run[r] = l;
  }

  const int orow0 = b * SS + qb + w * 16 + 4 * lg;
#pragma unroll
  for (int dg = 0; dg < 4; ++dg) {
    const int col = h * 64 + dg * 16 + lr;
#pragma unroll
    for (int r = 0; r < 4; ++r) {
      float v = o[dg][r] / l_run[r];
      ctx[(size_t)(orow0 + r) * DM + col] = __float2bfloat16(v);
    }
  }
}

// ---------------- launch ----------------
extern "C" void kernel_launch(void* const* d_in, const int* in_sizes, int n_in,
                              void* d_out, int out_size, void* d_ws, size_t ws_size,
                              hipStream_t stream) {
  const float* x   = (const float*)d_in[0];
  const float* W_q = (const float*)d_in[1];
  const float* W_k = (const float*)d_in[2];
  const float* W_v = (const float*)d_in[3];
  const float* W_o = (const float*)d_in[4];
  float* out = (float*)d_out;

  char* ws = (char*)d_ws;
  bf16* xb    = (bf16*)ws; ws += (size_t)ROWS * DM * 2;
  bf16* wqk   = (bf16*)ws; ws += (size_t)NQK * DM * 2;
  bf16* wv    = (bf16*)ws; ws += (size_t)(NG * DH) * DM * 2;
  bf16* wo    = (bf16*)ws; ws += (size_t)DM * DM * 2;
  bf16* qkbuf = (bf16*)ws; ws += (size_t)ROWS * NQK * 2;
  bf16* vtb   = (bf16*)ws; ws += (size_t)(NG * DH) * ROWS * 2;
  bf16* ctx   = (bf16*)ws; ws += (size_t)ROWS * DM * 2;

  {
    int n4;
    n4 = (ROWS * DM) / 4;
    cvt_f32_bf16<<<n4 / 256, 256, 0, stream>>>(x, xb, n4);
    n4 = (2048 * DM) / 4;
    cvt_f32_bf16<<<n4 / 256, 256, 0, stream>>>(W_q, wqk, n4);
    n4 = (512 * DM) / 4;
    cvt_f32_bf16<<<n4 / 256, 256, 0, stream>>>(W_k, wqk + (size_t)2048 * DM, n4);
    cvt_f32_bf16<<<n4 / 256, 256, 0, stream>>>(W_v, wv, n4);
    n4 = (DM * DM) / 4;
    cvt_f32_bf16<<<n4 / 256, 256, 0, stream>>>(W_o, wo, n4);
  }

  // QK projection with exp2-softmax scale folded into BOTH Q and K columns
  gemm_bt<bf16><<<dim3(NQK / 128, ROWS / 128), 256, 0, stream>>>(xb, wqk, qkbuf, ROWS, NQK, DM, ALPHA_QK);
  // V projection, transposed: vtb[512][4096] = wv @ xb^T
  gemm_bt<bf16><<<dim3(ROWS / 128, (NG * DH) / 128), 256, 0, stream>>>(wv, xb, vtb, NG * DH, ROWS, DM, 1.0f);
  // attention
  gqa_attn<<<dim3(SS / 64, BB * NH), 256, 0, stream>>>(qkbuf, vtb, ctx);
  // output projection: out[4096][2048] f32 = ctx @ wo^T
  gemm_bt<float><<<dim3(DM / 128, ROWS / 128), 256, 0, stream>>>(ctx, wo, out, ROWS, DM, DM, 1.0f);
}

// Round 4
// 286.223 us; speedup vs baseline: 1.2464x; 1.1425x over previous
//
#include <hip/hip_runtime.h>
#include <hip/hip_bf16.h>
#include <stdint.h>
#include <stddef.h>

typedef __hip_bfloat16 bf16;
typedef short bf16x8 __attribute__((ext_vector_type(8)));
typedef float f32x4 __attribute__((ext_vector_type(4)));

// Problem constants
#define BB 2
#define SS 2048
#define DM 2048
#define NH 32
#define NG 8
#define DH 64
#define ROWS (BB * SS)   // 4096
#define NQK 2560         // Q cols (2048) + K cols (512)

// sqrt(0.125 * log2(e)) — applied to BOTH Q and K columns in the QK-proj GEMM,
// so S = (aQ)(aK)^T arrives pre-scaled for exp2-domain softmax.
#define ALPHA_QK 0.4246609001440095f

__device__ __forceinline__ void gload_lds16(const void* g, void* l) {
  __builtin_amdgcn_global_load_lds((const __attribute__((address_space(1))) void*)g,
                                   (__attribute__((address_space(3))) void*)l, 16, 0, 0);
}

// ---------------- f32 -> bf16 convert, 4 elements/thread ----------------
__global__ __launch_bounds__(256) void cvt_f32_bf16(const float* __restrict__ in,
                                                    bf16* __restrict__ out, int n4) {
  int i = blockIdx.x * 256 + threadIdx.x;
  if (i >= n4) return;
  float4 v = reinterpret_cast<const float4*>(in)[i];
  bf16 t0 = __float2bfloat16(v.x), t1 = __float2bfloat16(v.y);
  bf16 t2 = __float2bfloat16(v.z), t3 = __float2bfloat16(v.w);
  ushort4 o;
  o.x = *reinterpret_cast<unsigned short*>(&t0);
  o.y = *reinterpret_cast<unsigned short*>(&t1);
  o.z = *reinterpret_cast<unsigned short*>(&t2);
  o.w = *reinterpret_cast<unsigned short*>(&t3);
  reinterpret_cast<ushort4*>(out)[i] = o;
}

// ---------------- GEMM: C[M][N] = alpha * A[M][K] * B[N][K]^T ----
// 2-phase double-buffered (T3-minimum): STAGE(next) issued before compute(cur).
__device__ __forceinline__ void store_elem(float* C, size_t i, float v) { C[i] = v; }
__device__ __forceinline__ void store_elem(bf16* C, size_t i, float v) { C[i] = __float2bfloat16(v); }

template <typename CT>
__global__ __launch_bounds__(256) void gemm_bt(const bf16* __restrict__ A,
                                               const bf16* __restrict__ Bm,
                                               CT* __restrict__ C,
                                               int M, int N, int K, float alpha) {
  const int t = threadIdx.x;
  const int w = t >> 6, lane = t & 63, lg = lane >> 4, lr = lane & 15;
  const int wr = w >> 1, wc = w & 1;
  const int rowA = blockIdx.y * 128, rowB = blockIdx.x * 128;
  __shared__ __align__(16) bf16 sA[2][128 * 32];
  __shared__ __align__(16) bf16 sB[2][128 * 32];
  f32x4 acc[4][4] = {};

  auto STAGE = [&](int bi, int k0) {
#pragma unroll
    for (int i = 0; i < 2; ++i) {
      const int c = i * 256 + t;           // 16B chunk index, 4 chunks/row
      const int r = c >> 2, slot = c & 3;
      const int ck = slot ^ ((r >> 1) & 3);
      gload_lds16(A + (size_t)(rowA + r) * K + k0 + ck * 8, &sA[bi][c * 8]);
      gload_lds16(Bm + (size_t)(rowB + r) * K + k0 + ck * 8, &sB[bi][c * 8]);
    }
  };

  STAGE(0, 0);
  asm volatile("s_waitcnt vmcnt(0)" ::: "memory");
  __syncthreads();
  int cur = 0;

  for (int k0 = 0; k0 < K; k0 += 32) {
    if (k0 + 32 < K) STAGE(cur ^ 1, k0 + 32);
    bf16x8 af[4], bfv[4];
#pragma unroll
    for (int mi = 0; mi < 4; ++mi) {
      const int r = wr * 64 + mi * 16 + lr;
      af[mi] = *(const bf16x8*)&sA[cur][r * 32 + (lg ^ ((r >> 1) & 3)) * 8];
    }
#pragma unroll
    for (int ni = 0; ni < 4; ++ni) {
      const int r = wc * 64 + ni * 16 + lr;
      bfv[ni] = *(const bf16x8*)&sB[cur][r * 32 + (lg ^ ((r >> 1) & 3)) * 8];
    }
#pragma unroll
    for (int mi = 0; mi < 4; ++mi)
#pragma unroll
      for (int ni = 0; ni < 4; ++ni)
        acc[mi][ni] = __builtin_amdgcn_mfma_f32_16x16x32_bf16(af[mi], bfv[ni], acc[mi][ni], 0, 0, 0);
    asm volatile("s_waitcnt vmcnt(0)" ::: "memory");
    __syncthreads();
    cur ^= 1;
  }
#pragma unroll
  for (int mi = 0; mi < 4; ++mi)
#pragma unroll
    for (int ni = 0; ni < 4; ++ni) {
      const int row0 = rowA + wr * 64 + mi * 16 + 4 * lg;
      const int col = rowB + wc * 64 + ni * 16 + lr;
#pragma unroll
      for (int r = 0; r < 4; ++r)
        store_elem(C, (size_t)(row0 + r) * N + col, acc[mi][ni][r] * alpha);
    }
}

// ---------------- fused GQA flash attention ----------------
// qk: [4096][2560] bf16, PRE-SCALED by sqrt(0.125*log2e) on both Q and K parts.
// vt: [512][4096] bf16 (row = g*64+d, col = b*2048+s)
// ctx: [4096][2048] bf16 out
// Block = 128 q-rows (4 waves x 32 rows), KV tile = 64, double-buffered.
__global__ __launch_bounds__(256, 3) void gqa_attn(const bf16* __restrict__ qk,
                                                   const bf16* __restrict__ vt,
                                                   bf16* __restrict__ ctx) {
  const int t = threadIdx.x, w = t >> 6, lane = t & 63, lg = lane >> 4, lr = lane & 15;
  const int head = blockIdx.y, b = head >> 5, h = head & 31, g = h >> 2;
  const int qb = blockIdx.x * 128;
  const size_t LD = NQK;
  const bf16* Qp = qk + (size_t)b * SS * LD + h * 64;
  const bf16* Kp = qk + (size_t)b * SS * LD + 2048 + g * 64;
  const bf16* Vt = vt + (size_t)(g * 64) * ROWS + b * SS;

  __shared__ __align__(16) bf16 sK[2][64 * 64];      // [key][d], slot-swizzled, dbuf
  __shared__ __align__(16) bf16 sV[2][64 * 64];      // [d][key], slot-swizzled, dbuf
  __shared__ __align__(16) bf16 sP[4][32 * 72];      // per-wave P (32 q-rows), stride 72

  // Q A-fragments: 2 row-blocks (mi) x 2 k-halves
  bf16x8 qf[2][2];
#pragma unroll
  for (int mi = 0; mi < 2; ++mi) {
    const bf16* qrow = Qp + (size_t)(qb + w * 32 + mi * 16 + lr) * LD;
    qf[mi][0] = *(const bf16x8*)(qrow + lg * 8);
    qf[mi][1] = *(const bf16x8*)(qrow + 32 + lg * 8);
  }

  // all-ones B-fragment (bf16 1.0 = 0x3F80) for l-from-MFMA
  const bf16x8 onesv = {0x3F80, 0x3F80, 0x3F80, 0x3F80, 0x3F80, 0x3F80, 0x3F80, 0x3F80};

  float m_run[2][4];
  f32x4 o[2][4];
  f32x4 lacc[2];
#pragma unroll
  for (int mi = 0; mi < 2; ++mi) {
    lacc[mi] = (f32x4){0.f, 0.f, 0.f, 0.f};
#pragma unroll
    for (int r = 0; r < 4; ++r) m_run[mi][r] = -3.0e38f;
#pragma unroll
    for (int dg = 0; dg < 4; ++dg) o[mi][dg] = (f32x4){0.f, 0.f, 0.f, 0.f};
  }

  auto STAGE = [&](int bi, int kt) {
#pragma unroll
    for (int i = 0; i < 2; ++i) {
      const int c = i * 256 + t;           // 16B chunk, 8 chunks/row
      const int r = c >> 3, slot = c & 7;
      const int ck = slot ^ (r & 7);
      gload_lds16(Kp + (size_t)(kt * 64 + r) * LD + ck * 8, &sK[bi][c * 8]);
      gload_lds16(Vt + (size_t)r * ROWS + kt * 64 + ck * 8, &sV[bi][c * 8]);
    }
  };

  STAGE(0, 0);
  __syncthreads();
  int cur = 0;

  for (int kt = 0; kt < SS / 64; ++kt) {
    if (kt + 1 < SS / 64) STAGE(cur ^ 1, kt + 1);

    // S = Q K^T  (s[mi][cg][reg] = S[mi*16+4*lg+reg][cg*16+lr]); exp2-scaled
    f32x4 s[2][4];
#pragma unroll
    for (int cg = 0; cg < 4; ++cg) {
      const int kr = cg * 16 + lr;
      bf16x8 kf0 = *(const bf16x8*)&sK[cur][kr * 64 + ((lg) ^ (kr & 7)) * 8];
      bf16x8 kf1 = *(const bf16x8*)&sK[cur][kr * 64 + ((lg + 4) ^ (kr & 7)) * 8];
#pragma unroll
      for (int mi = 0; mi < 2; ++mi) {
        f32x4 z = {0.f, 0.f, 0.f, 0.f};
        z = __builtin_amdgcn_mfma_f32_16x16x32_bf16(qf[mi][0], kf0, z, 0, 0, 0);
        z = __builtin_amdgcn_mfma_f32_16x16x32_bf16(qf[mi][1], kf1, z, 0, 0, 0);
        s[mi][cg] = z;
      }
    }

    // T13 defer-max: lane-local per-row max; full reduce+rescale only if needed
    float pm[2][4];
    bool ok = true;
#pragma unroll
    for (int mi = 0; mi < 2; ++mi)
#pragma unroll
      for (int r = 0; r < 4; ++r) {
        pm[mi][r] = fmaxf(fmaxf(s[0 + mi][0][r], s[mi][1][r]),
                          fmaxf(s[mi][2][r], s[mi][3][r]));
        ok = ok && (pm[mi][r] <= m_run[mi][r] + 8.f);
      }
    if (!__all(ok)) {
#pragma unroll
      for (int mi = 0; mi < 2; ++mi)
#pragma unroll
        for (int r = 0; r < 4; ++r) {
          float m = pm[mi][r];
          m = fmaxf(m, __shfl_xor(m, 1));
          m = fmaxf(m, __shfl_xor(m, 2));
          m = fmaxf(m, __shfl_xor(m, 4));
          m = fmaxf(m, __shfl_xor(m, 8));
          const float mn = fmaxf(m_run[mi][r], m);
          const float corr = __builtin_amdgcn_exp2f(m_run[mi][r] - mn);
          m_run[mi][r] = mn;
          lacc[mi][r] *= corr;
#pragma unroll
          for (int dg = 0; dg < 4; ++dg) o[mi][dg][r] *= corr;
        }
    }

    // P = exp2(s - m) (bounded by 2^8 under defer), park in wave-private LDS
    bf16* sPw = sP[w];
#pragma unroll
    for (int mi = 0; mi < 2; ++mi)
#pragma unroll
      for (int cg = 0; cg < 4; ++cg)
#pragma unroll
        for (int r = 0; r < 4; ++r) {
          float p = __builtin_amdgcn_exp2f(s[mi][cg][r] - m_run[mi][r]);
          sPw[(mi * 16 + 4 * lg + r) * 72 + cg * 16 + lr] = __float2bfloat16(p);
        }

    // O += P @ V ; l += P @ ones  (l rides the MFMA pipe)
#pragma unroll
    for (int kc = 0; kc < 2; ++kc) {
      bf16x8 pf[2];
#pragma unroll
      for (int mi = 0; mi < 2; ++mi)
        pf[mi] = *(const bf16x8*)&sPw[(mi * 16 + lr) * 72 + kc * 32 + lg * 8];
#pragma unroll
      for (int dg = 0; dg < 4; ++dg) {
        const int vr = dg * 16 + lr;
        bf16x8 vf = *(const bf16x8*)&sV[cur][vr * 64 + ((kc * 4 + lg) ^ (vr & 7)) * 8];
#pragma unroll
        for (int mi = 0; mi < 2; ++mi)
          o[mi][dg] = __builtin_amdgcn_mfma_f32_16x16x32_bf16(pf[mi], vf, o[mi][dg], 0, 0, 0);
      }
#pragma unroll
      for (int mi = 0; mi < 2; ++mi)
        lacc[mi] = __builtin_amdgcn_mfma_f32_16x16x32_bf16(pf[mi], onesv, lacc[mi], 0, 0, 0);
    }
    __syncthreads();
    cur ^= 1;
  }

  // l is complete per-row in lacc (replicated across cols) — no shfl reduce.
#pragma unroll
  for (int mi = 0; mi < 2; ++mi) {
    const int orow0 = b * SS + qb + w * 32 + mi * 16 + 4 * lg;
#pragma unroll
    for (int dg = 0; dg < 4; ++dg) {
      const int col = h * 64 + dg * 16 + lr;
#pragma unroll
      for (int r = 0; r < 4; ++r) {
        float v = o[mi][dg][r] / lacc[mi][r];
        ctx[(size_t)(orow0 + r) * DM + col] = __float2bfloat16(v);
      }
    }
  }
}

// ---------------- launch ----------------
extern "C" void kernel_launch(void* const* d_in, const int* in_sizes, int n_in,
                              void* d_out, int out_size, void* d_ws, size_t ws_size,
                              hipStream_t stream) {
  const float* x   = (const float*)d_in[0];
  const float* W_q = (const float*)d_in[1];
  const float* W_k = (const float*)d_in[2];
  const float* W_v = (const float*)d_in[3];
  const float* W_o = (const float*)d_in[4];
  float* out = (float*)d_out;

  char* ws = (char*)d_ws;
  bf16* xb    = (bf16*)ws; ws += (size_t)ROWS * DM * 2;
  bf16* wqk   = (bf16*)ws; ws += (size_t)NQK * DM * 2;
  bf16* wv    = (bf16*)ws; ws += (size_t)(NG * DH) * DM * 2;
  bf16* wo    = (bf16*)ws; ws += (size_t)DM * DM * 2;
  bf16* qkbuf = (bf16*)ws; ws += (size_t)ROWS * NQK * 2;
  bf16* vtb   = (bf16*)ws; ws += (size_t)(NG * DH) * ROWS * 2;
  bf16* ctx   = (bf16*)ws; ws += (size_t)ROWS * DM * 2;

  {
    int n4;
    n4 = (ROWS * DM) / 4;
    cvt_f32_bf16<<<n4 / 256, 256, 0, stream>>>(x, xb, n4);
    n4 = (2048 * DM) / 4;
    cvt_f32_bf16<<<n4 / 256, 256, 0, stream>>>(W_q, wqk, n4);
    n4 = (512 * DM) / 4;
    cvt_f32_bf16<<<n4 / 256, 256, 0, stream>>>(W_k, wqk + (size_t)2048 * DM, n4);
    cvt_f32_bf16<<<n4 / 256, 256, 0, stream>>>(W_v, wv, n4);
    n4 = (DM * DM) / 4;
    cvt_f32_bf16<<<n4 / 256, 256, 0, stream>>>(W_o, wo, n4);
  }

  // QK projection with exp2-softmax scale folded into BOTH Q and K columns
  gemm_bt<bf16><<<dim3(NQK / 128, ROWS / 128), 256, 0, stream>>>(xb, wqk, qkbuf, ROWS, NQK, DM, ALPHA_QK);
  // V projection, transposed: vtb[512][4096] = wv @ xb^T
  gemm_bt<bf16><<<dim3(ROWS / 128, (NG * DH) / 128), 256, 0, stream>>>(wv, xb, vtb, NG * DH, ROWS, DM, 1.0f);
  // attention: 128 q-rows per block
  gqa_attn<<<dim3(SS / 128, BB * NH), 256, 0, stream>>>(qkbuf, vtb, ctx);
  // output projection: out[4096][2048] f32 = ctx @ wo^T
  gemm_bt<float><<<dim3(DM / 128, ROWS / 128), 256, 0, stream>>>(ctx, wo, out, ROWS, DM, DM, 1.0f);
}

// Round 5
// 276.167 us; speedup vs baseline: 1.2918x; 1.0364x over previous
//
#include <hip/hip_runtime.h>
#include <hip/hip_bf16.h>
#include <stdint.h>
#include <stddef.h>

typedef __hip_bfloat16 bf16;
typedef short bf16x8 __attribute__((ext_vector_type(8)));
typedef float f32x4 __attribute__((ext_vector_type(4)));

// Problem constants
#define BB 2
#define SS 2048
#define DM 2048
#define NH 32
#define NG 8
#define DH 64
#define ROWS (BB * SS)   // 4096
#define NQK 2560         // Q cols (2048) + K cols (512)

// sqrt(0.125 * log2(e)) — applied to BOTH Q and K columns in the QK-proj GEMM,
// so S = (aQ)(aK)^T arrives pre-scaled for exp2-domain softmax.
#define ALPHA_QK 0.4246609001440095f

__device__ __forceinline__ void gload_lds16(const void* g, void* l) {
  __builtin_amdgcn_global_load_lds((const __attribute__((address_space(1))) void*)g,
                                   (__attribute__((address_space(3))) void*)l, 16, 0, 0);
}

// ---------------- f32 -> bf16 convert, 4 elements/thread ----------------
__global__ __launch_bounds__(256) void cvt_f32_bf16(const float* __restrict__ in,
                                                    bf16* __restrict__ out, int n4) {
  int i = blockIdx.x * 256 + threadIdx.x;
  if (i >= n4) return;
  float4 v = reinterpret_cast<const float4*>(in)[i];
  bf16 t0 = __float2bfloat16(v.x), t1 = __float2bfloat16(v.y);
  bf16 t2 = __float2bfloat16(v.z), t3 = __float2bfloat16(v.w);
  ushort4 o;
  o.x = *reinterpret_cast<unsigned short*>(&t0);
  o.y = *reinterpret_cast<unsigned short*>(&t1);
  o.z = *reinterpret_cast<unsigned short*>(&t2);
  o.w = *reinterpret_cast<unsigned short*>(&t3);
  reinterpret_cast<ushort4*>(out)[i] = o;
}

// ---------------- GEMM: C[M][N] = alpha * A[M][K] * B[N][K]^T ----
// 3-deep circular global_load_lds pipeline with COUNTED vmcnt (T4):
// loads for the next 2 K-steps stay in flight across barriers; never drain to 0.
__device__ __forceinline__ void store_elem(float* C, size_t i, float v) { C[i] = v; }
__device__ __forceinline__ void store_elem(bf16* C, size_t i, float v) { C[i] = __float2bfloat16(v); }

template <typename CT>
__global__ __launch_bounds__(256) void gemm_bt(const bf16* __restrict__ A,
                                               const bf16* __restrict__ Bm,
                                               CT* __restrict__ C,
                                               int M, int N, int K, float alpha) {
  const int t = threadIdx.x;
  const int w = t >> 6, lane = t & 63, lg = lane >> 4, lr = lane & 15;
  const int wr = w >> 1, wc = w & 1;
  const int rowA = blockIdx.y * 128, rowB = blockIdx.x * 128;
  __shared__ __align__(16) bf16 sA[3][128 * 32];   // 3-deep, 24 KB
  __shared__ __align__(16) bf16 sB[3][128 * 32];   // 24 KB
  f32x4 acc[4][4] = {};

  auto STAGE = [&](int bi, int k0) {               // 4 gload_lds / lane
#pragma unroll
    for (int i = 0; i < 2; ++i) {
      const int c = i * 256 + t;           // 16B chunk index, 4 chunks/row
      const int r = c >> 2, slot = c & 3;
      const int ck = slot ^ ((r >> 1) & 3);
      gload_lds16(A + (size_t)(rowA + r) * K + k0 + ck * 8, &sA[bi][c * 8]);
      gload_lds16(Bm + (size_t)(rowB + r) * K + k0 + ck * 8, &sB[bi][c * 8]);
    }
  };

  const int nt = K / 32;                   // = 64 here (K=2048), nt >= 3 assumed
  STAGE(0, 0);
  STAGE(1, 32);
  STAGE(2, 64);

  for (int i = 0; i < nt; ++i) {
    // wait for the OLDEST stage only; up to 2 stages (8 loads) stay in flight
    if (i <= nt - 3)      asm volatile("s_waitcnt vmcnt(8)" ::: "memory");
    else if (i == nt - 2) asm volatile("s_waitcnt vmcnt(4)" ::: "memory");
    else                  asm volatile("s_waitcnt vmcnt(0)" ::: "memory");
    __builtin_amdgcn_s_barrier();          // all waves' stage-i loads now visible

    const int bi = i % 3;
    bf16x8 af[4], bfv[4];
#pragma unroll
    for (int mi = 0; mi < 4; ++mi) {
      const int r = wr * 64 + mi * 16 + lr;
      af[mi] = *(const bf16x8*)&sA[bi][r * 32 + (lg ^ ((r >> 1) & 3)) * 8];
    }
#pragma unroll
    for (int ni = 0; ni < 4; ++ni) {
      const int r = wc * 64 + ni * 16 + lr;
      bfv[ni] = *(const bf16x8*)&sB[bi][r * 32 + (lg ^ ((r >> 1) & 3)) * 8];
    }
    // own LDS reads must retire before the overwrite barrier (rule #18 fence)
    asm volatile("s_waitcnt lgkmcnt(0)" ::: "memory");
    __builtin_amdgcn_sched_barrier(0);
    __builtin_amdgcn_s_barrier();          // all waves done reading buf bi
    if (i + 3 < nt) STAGE(bi, (i + 3) * 32);
#pragma unroll
    for (int mi = 0; mi < 4; ++mi)
#pragma unroll
      for (int ni = 0; ni < 4; ++ni)
        acc[mi][ni] = __builtin_amdgcn_mfma_f32_16x16x32_bf16(af[mi], bfv[ni], acc[mi][ni], 0, 0, 0);
  }

#pragma unroll
  for (int mi = 0; mi < 4; ++mi)
#pragma unroll
    for (int ni = 0; ni < 4; ++ni) {
      const int row0 = rowA + wr * 64 + mi * 16 + 4 * lg;
      const int col = rowB + wc * 64 + ni * 16 + lr;
#pragma unroll
      for (int r = 0; r < 4; ++r)
        store_elem(C, (size_t)(row0 + r) * N + col, acc[mi][ni][r] * alpha);
    }
}

// ---------------- fused GQA flash attention ----------------
// qk: [4096][2560] bf16, PRE-SCALED by sqrt(0.125*log2e) on both Q and K parts.
// vt: [512][4096] bf16 (row = g*64+d, col = b*2048+s)
// ctx: [4096][2048] bf16 out
// Block = 128 q-rows (4 waves x 32 rows), KV tile = 64, 2-deep counted-vmcnt dbuf.
__global__ __launch_bounds__(256, 3) void gqa_attn(const bf16* __restrict__ qk,
                                                   const bf16* __restrict__ vt,
                                                   bf16* __restrict__ ctx) {
  const int t = threadIdx.x, w = t >> 6, lane = t & 63, lg = lane >> 4, lr = lane & 15;
  const int head = blockIdx.y, b = head >> 5, h = head & 31, g = h >> 2;
  const int qb = blockIdx.x * 128;
  const size_t LD = NQK;
  const bf16* Qp = qk + (size_t)b * SS * LD + h * 64;
  const bf16* Kp = qk + (size_t)b * SS * LD + 2048 + g * 64;
  const bf16* Vt = vt + (size_t)(g * 64) * ROWS + b * SS;

  __shared__ __align__(16) bf16 sK[2][64 * 64];      // [key][d], slot-swizzled, dbuf
  __shared__ __align__(16) bf16 sV[2][64 * 64];      // [d][key], slot-swizzled, dbuf
  __shared__ __align__(16) bf16 sP[4][32 * 72];      // per-wave P (32 q-rows), stride 72

  // Q A-fragments: 2 row-blocks (mi) x 2 k-halves
  bf16x8 qf[2][2];
#pragma unroll
  for (int mi = 0; mi < 2; ++mi) {
    const bf16* qrow = Qp + (size_t)(qb + w * 32 + mi * 16 + lr) * LD;
    qf[mi][0] = *(const bf16x8*)(qrow + lg * 8);
    qf[mi][1] = *(const bf16x8*)(qrow + 32 + lg * 8);
  }
  // drain Q loads so in-loop vmcnt counting is deterministic (stages only)
  asm volatile("s_waitcnt vmcnt(0)" ::: "memory");

  // all-ones B-fragment (bf16 1.0 = 0x3F80) for l-from-MFMA
  const bf16x8 onesv = {0x3F80, 0x3F80, 0x3F80, 0x3F80, 0x3F80, 0x3F80, 0x3F80, 0x3F80};

  float m_run[2][4];
  f32x4 o[2][4];
  f32x4 lacc[2];
#pragma unroll
  for (int mi = 0; mi < 2; ++mi) {
    lacc[mi] = (f32x4){0.f, 0.f, 0.f, 0.f};
#pragma unroll
    for (int r = 0; r < 4; ++r) m_run[mi][r] = -3.0e38f;
#pragma unroll
    for (int dg = 0; dg < 4; ++dg) o[mi][dg] = (f32x4){0.f, 0.f, 0.f, 0.f};
  }

  auto STAGE = [&](int bi, int kt) {                 // 4 gload_lds / lane
#pragma unroll
    for (int i = 0; i < 2; ++i) {
      const int c = i * 256 + t;           // 16B chunk, 8 chunks/row
      const int r = c >> 3, slot = c & 7;
      const int ck = slot ^ (r & 7);
      gload_lds16(Kp + (size_t)(kt * 64 + r) * LD + ck * 8, &sK[bi][c * 8]);
      gload_lds16(Vt + (size_t)r * ROWS + kt * 64 + ck * 8, &sV[bi][c * 8]);
    }
  };

  const int NT = SS / 64;
  STAGE(0, 0);
  int cur = 0;

  for (int kt = 0; kt < NT; ++kt) {
    // issue next stage, then wait for the OLDEST stage only (counted vmcnt)
    if (kt + 1 < NT) {
      STAGE(cur ^ 1, kt + 1);
      asm volatile("s_waitcnt vmcnt(4)" ::: "memory");
    } else {
      asm volatile("s_waitcnt vmcnt(0)" ::: "memory");
    }
    __builtin_amdgcn_s_barrier();          // all waves' stage-kt loads visible

    // S = Q K^T  (s[mi][cg][reg] = S[mi*16+4*lg+reg][cg*16+lr]); exp2-scaled
    f32x4 s[2][4];
#pragma unroll
    for (int cg = 0; cg < 4; ++cg) {
      const int kr = cg * 16 + lr;
      bf16x8 kf0 = *(const bf16x8*)&sK[cur][kr * 64 + ((lg) ^ (kr & 7)) * 8];
      bf16x8 kf1 = *(const bf16x8*)&sK[cur][kr * 64 + ((lg + 4) ^ (kr & 7)) * 8];
#pragma unroll
      for (int mi = 0; mi < 2; ++mi) {
        f32x4 z = {0.f, 0.f, 0.f, 0.f};
        z = __builtin_amdgcn_mfma_f32_16x16x32_bf16(qf[mi][0], kf0, z, 0, 0, 0);
        z = __builtin_amdgcn_mfma_f32_16x16x32_bf16(qf[mi][1], kf1, z, 0, 0, 0);
        s[mi][cg] = z;
      }
    }

    // T13 defer-max: lane-local per-row max; full reduce+rescale only if needed
    float pm[2][4];
    bool ok = true;
#pragma unroll
    for (int mi = 0; mi < 2; ++mi)
#pragma unroll
      for (int r = 0; r < 4; ++r) {
        pm[mi][r] = fmaxf(fmaxf(s[mi][0][r], s[mi][1][r]),
                          fmaxf(s[mi][2][r], s[mi][3][r]));
        ok = ok && (pm[mi][r] <= m_run[mi][r] + 8.f);
      }
    if (!__all(ok)) {
#pragma unroll
      for (int mi = 0; mi < 2; ++mi)
#pragma unroll
        for (int r = 0; r < 4; ++r) {
          float m = pm[mi][r];
          m = fmaxf(m, __shfl_xor(m, 1));
          m = fmaxf(m, __shfl_xor(m, 2));
          m = fmaxf(m, __shfl_xor(m, 4));
          m = fmaxf(m, __shfl_xor(m, 8));
          const float mn = fmaxf(m_run[mi][r], m);
          const float corr = __builtin_amdgcn_exp2f(m_run[mi][r] - mn);
          m_run[mi][r] = mn;
          lacc[mi][r] *= corr;
#pragma unroll
          for (int dg = 0; dg < 4; ++dg) o[mi][dg][r] *= corr;
        }
    }

    // P = exp2(s - m) (bounded by 2^8 under defer), park in wave-private LDS
    bf16* sPw = sP[w];
#pragma unroll
    for (int mi = 0; mi < 2; ++mi)
#pragma unroll
      for (int cg = 0; cg < 4; ++cg)
#pragma unroll
        for (int r = 0; r < 4; ++r) {
          float p = __builtin_amdgcn_exp2f(s[mi][cg][r] - m_run[mi][r]);
          sPw[(mi * 16 + 4 * lg + r) * 72 + cg * 16 + lr] = __float2bfloat16(p);
        }

    // O += P @ V ; l += P @ ones  (l rides the MFMA pipe)
#pragma unroll
    for (int kc = 0; kc < 2; ++kc) {
      bf16x8 pf[2];
#pragma unroll
      for (int mi = 0; mi < 2; ++mi)
        pf[mi] = *(const bf16x8*)&sPw[(mi * 16 + lr) * 72 + kc * 32 + lg * 8];
#pragma unroll
      for (int dg = 0; dg < 4; ++dg) {
        const int vr = dg * 16 + lr;
        bf16x8 vf = *(const bf16x8*)&sV[cur][vr * 64 + ((kc * 4 + lg) ^ (vr & 7)) * 8];
#pragma unroll
        for (int mi = 0; mi < 2; ++mi)
          o[mi][dg] = __builtin_amdgcn_mfma_f32_16x16x32_bf16(pf[mi], vf, o[mi][dg], 0, 0, 0);
      }
#pragma unroll
      for (int mi = 0; mi < 2; ++mi)
        lacc[mi] = __builtin_amdgcn_mfma_f32_16x16x32_bf16(pf[mi], onesv, lacc[mi], 0, 0, 0);
    }

    // own LDS ops retired before the overwrite barrier (rule #18 fence)
    asm volatile("s_waitcnt lgkmcnt(0)" ::: "memory");
    __builtin_amdgcn_sched_barrier(0);
    __builtin_amdgcn_s_barrier();          // all waves done with buf cur
    cur ^= 1;
  }

  // l is complete per-row in lacc (replicated across cols) — no shfl reduce.
#pragma unroll
  for (int mi = 0; mi < 2; ++mi) {
    const int orow0 = b * SS + qb + w * 32 + mi * 16 + 4 * lg;
#pragma unroll
    for (int dg = 0; dg < 4; ++dg) {
      const int col = h * 64 + dg * 16 + lr;
#pragma unroll
      for (int r = 0; r < 4; ++r) {
        float v = o[mi][dg][r] / lacc[mi][r];
        ctx[(size_t)(orow0 + r) * DM + col] = __float2bfloat16(v);
      }
    }
  }
}

// ---------------- launch ----------------
extern "C" void kernel_launch(void* const* d_in, const int* in_sizes, int n_in,
                              void* d_out, int out_size, void* d_ws, size_t ws_size,
                              hipStream_t stream) {
  const float* x   = (const float*)d_in[0];
  const float* W_q = (const float*)d_in[1];
  const float* W_k = (const float*)d_in[2];
  const float* W_v = (const float*)d_in[3];
  const float* W_o = (const float*)d_in[4];
  float* out = (float*)d_out;

  char* ws = (char*)d_ws;
  bf16* xb    = (bf16*)ws; ws += (size_t)ROWS * DM * 2;
  bf16* wqk   = (bf16*)ws; ws += (size_t)NQK * DM * 2;
  bf16* wv    = (bf16*)ws; ws += (size_t)(NG * DH) * DM * 2;
  bf16* wo    = (bf16*)ws; ws += (size_t)DM * DM * 2;
  bf16* qkbuf = (bf16*)ws; ws += (size_t)ROWS * NQK * 2;
  bf16* vtb   = (bf16*)ws; ws += (size_t)(NG * DH) * ROWS * 2;
  bf16* ctx   = (bf16*)ws; ws += (size_t)ROWS * DM * 2;

  {
    int n4;
    n4 = (ROWS * DM) / 4;
    cvt_f32_bf16<<<n4 / 256, 256, 0, stream>>>(x, xb, n4);
    n4 = (2048 * DM) / 4;
    cvt_f32_bf16<<<n4 / 256, 256, 0, stream>>>(W_q, wqk, n4);
    n4 = (512 * DM) / 4;
    cvt_f32_bf16<<<n4 / 256, 256, 0, stream>>>(W_k, wqk + (size_t)2048 * DM, n4);
    cvt_f32_bf16<<<n4 / 256, 256, 0, stream>>>(W_v, wv, n4);
    n4 = (DM * DM) / 4;
    cvt_f32_bf16<<<n4 / 256, 256, 0, stream>>>(W_o, wo, n4);
  }

  // QK projection with exp2-softmax scale folded into BOTH Q and K columns
  gemm_bt<bf16><<<dim3(NQK / 128, ROWS / 128), 256, 0, stream>>>(xb, wqk, qkbuf, ROWS, NQK, DM, ALPHA_QK);
  // V projection, transposed: vtb[512][4096] = wv @ xb^T
  gemm_bt<bf16><<<dim3(ROWS / 128, (NG * DH) / 128), 256, 0, stream>>>(wv, xb, vtb, NG * DH, ROWS, DM, 1.0f);
  // attention: 128 q-rows per block
  gqa_attn<<<dim3(SS / 128, BB * NH), 256, 0, stream>>>(qkbuf, vtb, ctx);
  // output projection: out[4096][2048] f32 = ctx @ wo^T
  gemm_bt<float><<<dim3(DM / 128, ROWS / 128), 256, 0, stream>>>(ctx, wo, out, ROWS, DM, DM, 1.0f);
}

// Round 6
// 259.138 us; speedup vs baseline: 1.3767x; 1.0657x over previous
//
#include <hip/hip_runtime.h>
#include <hip/hip_bf16.h>
#include <stdint.h>
#include <stddef.h>

typedef __hip_bfloat16 bf16;
typedef short bf16x8 __attribute__((ext_vector_type(8)));
typedef float f32x4 __attribute__((ext_vector_type(4)));

// Problem constants
#define BB 2
#define SS 2048
#define DM 2048
#define NH 32
#define NG 8
#define DH 64
#define ROWS (BB * SS)   // 4096
#define NQK 2560         // Q cols (2048) + K cols (512)

// sqrt(0.125 * log2(e)) — applied to BOTH Q and K columns in the QK-proj GEMM,
// so S = (aQ)(aK)^T arrives pre-scaled for exp2-domain softmax.
#define ALPHA_QK 0.4246609001440095f

__device__ __forceinline__ void gload_lds16(const void* g, void* l) {
  __builtin_amdgcn_global_load_lds((const __attribute__((address_space(1))) void*)g,
                                   (__attribute__((address_space(3))) void*)l, 16, 0, 0);
}

__device__ __forceinline__ unsigned cvt_pk_bf16(float lo, float hi) {
  unsigned r;
  asm("v_cvt_pk_bf16_f32 %0, %1, %2" : "=v"(r) : "v"(lo), "v"(hi));
  return r;
}

// ---------------- f32 -> bf16 convert, 4 elements/thread ----------------
__global__ __launch_bounds__(256) void cvt_f32_bf16(const float* __restrict__ in,
                                                    bf16* __restrict__ out, int n4) {
  int i = blockIdx.x * 256 + threadIdx.x;
  if (i >= n4) return;
  float4 v = reinterpret_cast<const float4*>(in)[i];
  bf16 t0 = __float2bfloat16(v.x), t1 = __float2bfloat16(v.y);
  bf16 t2 = __float2bfloat16(v.z), t3 = __float2bfloat16(v.w);
  ushort4 o;
  o.x = *reinterpret_cast<unsigned short*>(&t0);
  o.y = *reinterpret_cast<unsigned short*>(&t1);
  o.z = *reinterpret_cast<unsigned short*>(&t2);
  o.w = *reinterpret_cast<unsigned short*>(&t3);
  reinterpret_cast<ushort4*>(out)[i] = o;
}

// ---------------- GEMM: C[M][N] = alpha * A[M][K] * B[N][K]^T ----
// 3-deep circular global_load_lds pipeline with COUNTED vmcnt (T4).
__device__ __forceinline__ void store_elem(float* C, size_t i, float v) { C[i] = v; }
__device__ __forceinline__ void store_elem(bf16* C, size_t i, float v) { C[i] = __float2bfloat16(v); }

template <typename CT>
__global__ __launch_bounds__(256) void gemm_bt(const bf16* __restrict__ A,
                                               const bf16* __restrict__ Bm,
                                               CT* __restrict__ C,
                                               int M, int N, int K, float alpha) {
  const int t = threadIdx.x;
  const int w = t >> 6, lane = t & 63, lg = lane >> 4, lr = lane & 15;
  const int wr = w >> 1, wc = w & 1;
  const int rowA = blockIdx.y * 128, rowB = blockIdx.x * 128;
  __shared__ __align__(16) bf16 sA[3][128 * 32];
  __shared__ __align__(16) bf16 sB[3][128 * 32];
  f32x4 acc[4][4] = {};

  auto STAGE = [&](int bi, int k0) {               // 4 gload_lds / lane
#pragma unroll
    for (int i = 0; i < 2; ++i) {
      const int c = i * 256 + t;           // 16B chunk index, 4 chunks/row
      const int r = c >> 2, slot = c & 3;
      const int ck = slot ^ ((r >> 1) & 3);
      gload_lds16(A + (size_t)(rowA + r) * K + k0 + ck * 8, &sA[bi][c * 8]);
      gload_lds16(Bm + (size_t)(rowB + r) * K + k0 + ck * 8, &sB[bi][c * 8]);
    }
  };

  const int nt = K / 32;
  STAGE(0, 0);
  STAGE(1, 32);
  STAGE(2, 64);

  for (int i = 0; i < nt; ++i) {
    if (i <= nt - 3)      asm volatile("s_waitcnt vmcnt(8)" ::: "memory");
    else if (i == nt - 2) asm volatile("s_waitcnt vmcnt(4)" ::: "memory");
    else                  asm volatile("s_waitcnt vmcnt(0)" ::: "memory");
    __builtin_amdgcn_s_barrier();

    const int bi = i % 3;
    bf16x8 af[4], bfv[4];
#pragma unroll
    for (int mi = 0; mi < 4; ++mi) {
      const int r = wr * 64 + mi * 16 + lr;
      af[mi] = *(const bf16x8*)&sA[bi][r * 32 + (lg ^ ((r >> 1) & 3)) * 8];
    }
#pragma unroll
    for (int ni = 0; ni < 4; ++ni) {
      const int r = wc * 64 + ni * 16 + lr;
      bfv[ni] = *(const bf16x8*)&sB[bi][r * 32 + (lg ^ ((r >> 1) & 3)) * 8];
    }
    asm volatile("s_waitcnt lgkmcnt(0)" ::: "memory");
    __builtin_amdgcn_sched_barrier(0);
    __builtin_amdgcn_s_barrier();
    if (i + 3 < nt) STAGE(bi, (i + 3) * 32);
#pragma unroll
    for (int mi = 0; mi < 4; ++mi)
#pragma unroll
      for (int ni = 0; ni < 4; ++ni)
        acc[mi][ni] = __builtin_amdgcn_mfma_f32_16x16x32_bf16(af[mi], bfv[ni], acc[mi][ni], 0, 0, 0);
  }

#pragma unroll
  for (int mi = 0; mi < 4; ++mi)
#pragma unroll
    for (int ni = 0; ni < 4; ++ni) {
      const int row0 = rowA + wr * 64 + mi * 16 + 4 * lg;
      const int col = rowB + wc * 64 + ni * 16 + lr;
#pragma unroll
      for (int r = 0; r < 4; ++r)
        store_elem(C, (size_t)(row0 + r) * N + col, acc[mi][ni][r] * alpha);
    }
}

// ---------------- fused GQA flash attention (swapped QK^T, T12-style) -------
// qk: [4096][2560] bf16, PRE-SCALED by sqrt(0.125*log2e) on both Q and K parts.
// vt: [512][4096] bf16 (row = g*64+d, col = b*2048+s)
// ctx: [4096][2048] bf16 out
// Block = 128 q-rows (4 waves x 32 rows), KV tile = 64, 2-deep counted-vmcnt dbuf.
// S^T = mfma(K_frag, Q_frag): lane holds S[k=cg*16+4lg+r][q=lr] -> softmax for
// q=lr is LANE-LOCAL; P packs k-consecutively -> ds_write_b64 instead of b16 x4.
__global__ __launch_bounds__(256, 3) void gqa_attn(const bf16* __restrict__ qk,
                                                   const bf16* __restrict__ vt,
                                                   bf16* __restrict__ ctx) {
  const int t = threadIdx.x, w = t >> 6, lane = t & 63, lg = lane >> 4, lr = lane & 15;
  const int head = blockIdx.y, b = head >> 5, h = head & 31, g = h >> 2;
  const int qb = blockIdx.x * 128;
  const size_t LD = NQK;
  const bf16* Qp = qk + (size_t)b * SS * LD + h * 64;
  const bf16* Kp = qk + (size_t)b * SS * LD + 2048 + g * 64;
  const bf16* Vt = vt + (size_t)(g * 64) * ROWS + b * SS;

  __shared__ __align__(16) bf16 sK[2][64 * 64];      // [key][d], slot-swizzled, dbuf
  __shared__ __align__(16) bf16 sV[2][64 * 64];      // [d][key], slot-swizzled, dbuf
  __shared__ __align__(16) bf16 sP[4][32 * 72];      // per-wave P (32 q-rows), stride 72

  // Q B-fragments (Q^T as B-operand): lane holds q=lr, d = 8*lg+j — same loads.
  bf16x8 qf[2][2];
#pragma unroll
  for (int mi = 0; mi < 2; ++mi) {
    const bf16* qrow = Qp + (size_t)(qb + w * 32 + mi * 16 + lr) * LD;
    qf[mi][0] = *(const bf16x8*)(qrow + lg * 8);
    qf[mi][1] = *(const bf16x8*)(qrow + 32 + lg * 8);
  }
  asm volatile("s_waitcnt vmcnt(0)" ::: "memory");   // deterministic vmcnt counting

  float m_run[2], l_part[2];                          // per-lane: q = lr (per mi)
  f32x4 o[2][4];
#pragma unroll
  for (int mi = 0; mi < 2; ++mi) {
    m_run[mi] = -3.0e38f;
    l_part[mi] = 0.0f;
#pragma unroll
    for (int dg = 0; dg < 4; ++dg) o[mi][dg] = (f32x4){0.f, 0.f, 0.f, 0.f};
  }

  auto STAGE = [&](int bi, int kt) {                 // 4 gload_lds / lane
#pragma unroll
    for (int i = 0; i < 2; ++i) {
      const int c = i * 256 + t;           // 16B chunk, 8 chunks/row
      const int r = c >> 3, slot = c & 7;
      const int ck = slot ^ (r & 7);
      gload_lds16(Kp + (size_t)(kt * 64 + r) * LD + ck * 8, &sK[bi][c * 8]);
      gload_lds16(Vt + (size_t)r * ROWS + kt * 64 + ck * 8, &sV[bi][c * 8]);
    }
  };

  const int NT = SS / 64;
  STAGE(0, 0);
  int cur = 0;

  for (int kt = 0; kt < NT; ++kt) {
    if (kt + 1 < NT) {
      STAGE(cur ^ 1, kt + 1);
      asm volatile("s_waitcnt vmcnt(4)" ::: "memory");
    } else {
      asm volatile("s_waitcnt vmcnt(0)" ::: "memory");
    }
    __builtin_amdgcn_s_barrier();

    // S^T = K Q^T  (s[mi][cg][r] = S[q = lr][k = cg*16 + 4*lg + r])
    f32x4 s[2][4];
    __builtin_amdgcn_s_setprio(1);
#pragma unroll
    for (int cg = 0; cg < 4; ++cg) {
      const int kr = cg * 16 + lr;
      bf16x8 kf0 = *(const bf16x8*)&sK[cur][kr * 64 + ((lg) ^ (kr & 7)) * 8];
      bf16x8 kf1 = *(const bf16x8*)&sK[cur][kr * 64 + ((lg + 4) ^ (kr & 7)) * 8];
#pragma unroll
      for (int mi = 0; mi < 2; ++mi) {
        f32x4 z = {0.f, 0.f, 0.f, 0.f};
        z = __builtin_amdgcn_mfma_f32_16x16x32_bf16(kf0, qf[mi][0], z, 0, 0, 0);
        z = __builtin_amdgcn_mfma_f32_16x16x32_bf16(kf1, qf[mi][1], z, 0, 0, 0);
        s[mi][cg] = z;
      }
    }
    __builtin_amdgcn_s_setprio(0);

    // T13 defer-max: lane-local max over this lane's 16 k-values (its q-row slice)
    float pm[2];
    bool ok = true;
#pragma unroll
    for (int mi = 0; mi < 2; ++mi) {
      float m01 = fmaxf(fmaxf(s[mi][0][0], s[mi][0][1]), fmaxf(s[mi][0][2], s[mi][0][3]));
      float m1 = fmaxf(fmaxf(s[mi][1][0], s[mi][1][1]), fmaxf(s[mi][1][2], s[mi][1][3]));
      float m2 = fmaxf(fmaxf(s[mi][2][0], s[mi][2][1]), fmaxf(s[mi][2][2], s[mi][2][3]));
      float m3 = fmaxf(fmaxf(s[mi][3][0], s[mi][3][1]), fmaxf(s[mi][3][2], s[mi][3][3]));
      pm[mi] = fmaxf(fmaxf(m01, m1), fmaxf(m2, m3));
      ok = ok && (pm[mi] <= m_run[mi] + 8.f);
    }
    if (!__all(ok)) {
#pragma unroll
      for (int mi = 0; mi < 2; ++mi) {
        float m = pm[mi];
        m = fmaxf(m, __shfl_xor(m, 16));   // reduce across the 4 lg-groups
        m = fmaxf(m, __shfl_xor(m, 32));
        const float mn = fmaxf(m_run[mi], m);
        const float corr = __builtin_amdgcn_exp2f(m_run[mi] - mn);
        m_run[mi] = mn;
        l_part[mi] *= corr;
        // O rows live at q_local = 4*lg + r — fetch corr from the lane owning that q
#pragma unroll
        for (int r = 0; r < 4; ++r) {
          const float co = __shfl(corr, 20 * lg + r);
#pragma unroll
          for (int dg = 0; dg < 4; ++dg) o[mi][dg][r] *= co;
        }
      }
    }

    // P = exp2(s - m): lane-local q-row; pack pairs (k-consecutive) -> b64 writes
    bf16* sPw = sP[w];
#pragma unroll
    for (int mi = 0; mi < 2; ++mi) {
#pragma unroll
      for (int cg = 0; cg < 4; ++cg) {
        float p0 = __builtin_amdgcn_exp2f(s[mi][cg][0] - m_run[mi]);
        float p1 = __builtin_amdgcn_exp2f(s[mi][cg][1] - m_run[mi]);
        float p2 = __builtin_amdgcn_exp2f(s[mi][cg][2] - m_run[mi]);
        float p3 = __builtin_amdgcn_exp2f(s[mi][cg][3] - m_run[mi]);
        l_part[mi] += (p0 + p1) + (p2 + p3);
        uint2 pk;
        pk.x = cvt_pk_bf16(p0, p1);
        pk.y = cvt_pk_bf16(p2, p3);
        *(uint2*)&sPw[(mi * 16 + lr) * 72 + cg * 16 + 4 * lg] = pk;
      }
    }

    // O += P @ V  (A = P [16 q][64 k], B = V [64 k][16 d])
#pragma unroll
    for (int kc = 0; kc < 2; ++kc) {
      bf16x8 pf[2];
#pragma unroll
      for (int mi = 0; mi < 2; ++mi)
        pf[mi] = *(const bf16x8*)&sPw[(mi * 16 + lr) * 72 + kc * 32 + lg * 8];
      __builtin_amdgcn_s_setprio(1);
#pragma unroll
      for (int dg = 0; dg < 4; ++dg) {
        const int vr = dg * 16 + lr;
        bf16x8 vf = *(const bf16x8*)&sV[cur][vr * 64 + ((kc * 4 + lg) ^ (vr & 7)) * 8];
#pragma unroll
        for (int mi = 0; mi < 2; ++mi)
          o[mi][dg] = __builtin_amdgcn_mfma_f32_16x16x32_bf16(pf[mi], vf, o[mi][dg], 0, 0, 0);
      }
      __builtin_amdgcn_s_setprio(0);
    }

    asm volatile("s_waitcnt lgkmcnt(0)" ::: "memory");
    __builtin_amdgcn_sched_barrier(0);
    __builtin_amdgcn_s_barrier();
    cur ^= 1;
  }

  // final l: sum across lg-groups (q = lr), then hop to O layout (q = 4*lg + r)
#pragma unroll
  for (int mi = 0; mi < 2; ++mi) {
    float l = l_part[mi];
    l += __shfl_xor(l, 16);
    l += __shfl_xor(l, 32);
    const int orow0 = b * SS + qb + w * 32 + mi * 16 + 4 * lg;
#pragma unroll
    for (int r = 0; r < 4; ++r) {
      const float lo = __shfl(l, 20 * lg + r);
      const float inv = 1.0f / lo;
      const int row = orow0 + r;
#pragma unroll
      for (int dg = 0; dg < 4; ++dg) {
        const int col = h * 64 + dg * 16 + lr;
        ctx[(size_t)row * DM + col] = __float2bfloat16(o[mi][dg][r] * inv);
      }
    }
  }
}

// ---------------- launch ----------------
extern "C" void kernel_launch(void* const* d_in, const int* in_sizes, int n_in,
                              void* d_out, int out_size, void* d_ws, size_t ws_size,
                              hipStream_t stream) {
  const float* x   = (const float*)d_in[0];
  const float* W_q = (const float*)d_in[1];
  const float* W_k = (const float*)d_in[2];
  const float* W_v = (const float*)d_in[3];
  const float* W_o = (const float*)d_in[4];
  float* out = (float*)d_out;

  char* ws = (char*)d_ws;
  bf16* xb    = (bf16*)ws; ws += (size_t)ROWS * DM * 2;
  bf16* wqk   = (bf16*)ws; ws += (size_t)NQK * DM * 2;
  bf16* wv    = (bf16*)ws; ws += (size_t)(NG * DH) * DM * 2;
  bf16* wo    = (bf16*)ws; ws += (size_t)DM * DM * 2;
  bf16* qkbuf = (bf16*)ws; ws += (size_t)ROWS * NQK * 2;
  bf16* vtb   = (bf16*)ws; ws += (size_t)(NG * DH) * ROWS * 2;
  bf16* ctx   = (bf16*)ws; ws += (size_t)ROWS * DM * 2;

  {
    int n4;
    n4 = (ROWS * DM) / 4;
    cvt_f32_bf16<<<n4 / 256, 256, 0, stream>>>(x, xb, n4);
    n4 = (2048 * DM) / 4;
    cvt_f32_bf16<<<n4 / 256, 256, 0, stream>>>(W_q, wqk, n4);
    n4 = (512 * DM) / 4;
    cvt_f32_bf16<<<n4 / 256, 256, 0, stream>>>(W_k, wqk + (size_t)2048 * DM, n4);
    cvt_f32_bf16<<<n4 / 256, 256, 0, stream>>>(W_v, wv, n4);
    n4 = (DM * DM) / 4;
    cvt_f32_bf16<<<n4 / 256, 256, 0, stream>>>(W_o, wo, n4);
  }

  // QK projection with exp2-softmax scale folded into BOTH Q and K columns
  gemm_bt<bf16><<<dim3(NQK / 128, ROWS / 128), 256, 0, stream>>>(xb, wqk, qkbuf, ROWS, NQK, DM, ALPHA_QK);
  // V projection, transposed: vtb[512][4096] = wv @ xb^T
  gemm_bt<bf16><<<dim3(ROWS / 128, (NG * DH) / 128), 256, 0, stream>>>(wv, xb, vtb, NG * DH, ROWS, DM, 1.0f);
  // attention: 128 q-rows per block
  gqa_attn<<<dim3(SS / 128, BB * NH), 256, 0, stream>>>(qkbuf, vtb, ctx);
  // output projection: out[4096][2048] f32 = ctx @ wo^T
  gemm_bt<float><<<dim3(DM / 128, ROWS / 128), 256, 0, stream>>>(ctx, wo, out, ROWS, DM, DM, 1.0f);
}

// Round 8
// 244.349 us; speedup vs baseline: 1.4600x; 1.0605x over previous
//
#include <hip/hip_runtime.h>
#include <hip/hip_bf16.h>
#include <stdint.h>
#include <stddef.h>

typedef __hip_bfloat16 bf16;
typedef short bf16x8 __attribute__((ext_vector_type(8)));
typedef float f32x4 __attribute__((ext_vector_type(4)));

// Problem constants
#define BB 2
#define SS 2048
#define DM 2048
#define NH 32
#define NG 8
#define DH 64
#define ROWS (BB * SS)   // 4096
#define NQK 2560         // Q cols (2048) + K cols (512)

// sqrt(0.125 * log2(e)) — applied to BOTH Q and K columns in the QK-proj GEMM,
// so S = (aQ)(aK)^T arrives pre-scaled for exp2-domain softmax.
#define ALPHA_QK 0.4246609001440095f

__device__ __forceinline__ void gload_lds16(const void* g, void* l) {
  __builtin_amdgcn_global_load_lds((const __attribute__((address_space(1))) void*)g,
                                   (__attribute__((address_space(3))) void*)l, 16, 0, 0);
}

__device__ __forceinline__ unsigned cvt_pk_bf16(float lo, float hi) {
  unsigned r;
  asm("v_cvt_pk_bf16_f32 %0, %1, %2" : "=v"(r) : "v"(lo), "v"(hi));
  return r;
}

// ---------------- fused f32 -> bf16 convert for all 5 inputs ----------------
// chunk ranges (float4 units): x 0..2097152, W_q ..3145728, W_k ..3407872,
// W_v ..3670016, W_o ..4718592. All range starts are multiples of 256 so
// branches are block-uniform.
__global__ __launch_bounds__(256) void cvt_all(const float* __restrict__ x,
                                               const float* __restrict__ wq,
                                               const float* __restrict__ wk,
                                               const float* __restrict__ wv,
                                               const float* __restrict__ wo,
                                               bf16* __restrict__ xb,
                                               bf16* __restrict__ wqkb,
                                               bf16* __restrict__ wvb,
                                               bf16* __restrict__ wob) {
  const int i = blockIdx.x * 256 + threadIdx.x;
  const float* src;
  bf16* dst;
  if (i < 2097152)       { src = x  + (size_t)i * 4;              dst = xb   + (size_t)i * 4; }
  else if (i < 3145728)  { size_t j = i - 2097152; src = wq + j * 4; dst = wqkb + j * 4; }
  else if (i < 3407872)  { size_t j = i - 3145728; src = wk + j * 4; dst = wqkb + 4194304 + j * 4; }
  else if (i < 3670016)  { size_t j = i - 3407872; src = wv + j * 4; dst = wvb  + j * 4; }
  else                   { size_t j = i - 3670016; src = wo + j * 4; dst = wob  + j * 4; }
  float4 v = *reinterpret_cast<const float4*>(src);
  bf16 t0 = __float2bfloat16(v.x), t1 = __float2bfloat16(v.y);
  bf16 t2 = __float2bfloat16(v.z), t3 = __float2bfloat16(v.w);
  ushort4 o;
  o.x = *reinterpret_cast<unsigned short*>(&t0);
  o.y = *reinterpret_cast<unsigned short*>(&t1);
  o.z = *reinterpret_cast<unsigned short*>(&t2);
  o.w = *reinterpret_cast<unsigned short*>(&t3);
  *reinterpret_cast<ushort4*>(dst) = o;
}

// ---------------- GEMM: C[M][N] = alpha * A[M][K] * B[N][K]^T ----
// 3-deep circular global_load_lds pipeline with COUNTED vmcnt (T4).
// T1 XCD swizzle on the flattened block index (requires nwg % 8 == 0 —
// true for all three launches here: 640, 128, 512).
__device__ __forceinline__ void store_elem(float* C, size_t i, float v) { C[i] = v; }
__device__ __forceinline__ void store_elem(bf16* C, size_t i, float v) { C[i] = __float2bfloat16(v); }

template <typename CT>
__global__ __launch_bounds__(256) void gemm_bt(const bf16* __restrict__ A,
                                               const bf16* __restrict__ Bm,
                                               CT* __restrict__ C,
                                               int M, int N, int K, float alpha) {
  const int t = threadIdx.x;
  const int w = t >> 6, lane = t & 63, lg = lane >> 4, lr = lane & 15;
  const int wr = w >> 1, wc = w & 1;
  // XCD-contiguous swizzle (bijective when nwg % 8 == 0)
  const int nwg = gridDim.x * gridDim.y;
  const int flat = blockIdx.y * gridDim.x + blockIdx.x;
  const int swz = (flat & 7) * (nwg >> 3) + (flat >> 3);
  const int rowA = (swz / gridDim.x) * 128, rowB = (swz % gridDim.x) * 128;
  __shared__ __align__(16) bf16 sA[3][128 * 32];
  __shared__ __align__(16) bf16 sB[3][128 * 32];
  f32x4 acc[4][4] = {};

  auto STAGE = [&](int bi, int k0) {               // 4 gload_lds / lane
#pragma unroll
    for (int i = 0; i < 2; ++i) {
      const int c = i * 256 + t;           // 16B chunk index, 4 chunks/row
      const int r = c >> 2, slot = c & 3;
      const int ck = slot ^ ((r >> 1) & 3);
      gload_lds16(A + (size_t)(rowA + r) * K + k0 + ck * 8, &sA[bi][c * 8]);
      gload_lds16(Bm + (size_t)(rowB + r) * K + k0 + ck * 8, &sB[bi][c * 8]);
    }
  };

  const int nt = K / 32;
  STAGE(0, 0);
  STAGE(1, 32);
  STAGE(2, 64);

  for (int i = 0; i < nt; ++i) {
    if (i <= nt - 3)      asm volatile("s_waitcnt vmcnt(8)" ::: "memory");
    else if (i == nt - 2) asm volatile("s_waitcnt vmcnt(4)" ::: "memory");
    else                  asm volatile("s_waitcnt vmcnt(0)" ::: "memory");
    __builtin_amdgcn_s_barrier();

    const int bi = i % 3;
    bf16x8 af[4], bfv[4];
#pragma unroll
    for (int mi = 0; mi < 4; ++mi) {
      const int r = wr * 64 + mi * 16 + lr;
      af[mi] = *(const bf16x8*)&sA[bi][r * 32 + (lg ^ ((r >> 1) & 3)) * 8];
    }
#pragma unroll
    for (int ni = 0; ni < 4; ++ni) {
      const int r = wc * 64 + ni * 16 + lr;
      bfv[ni] = *(const bf16x8*)&sB[bi][r * 32 + (lg ^ ((r >> 1) & 3)) * 8];
    }
    asm volatile("s_waitcnt lgkmcnt(0)" ::: "memory");
    __builtin_amdgcn_sched_barrier(0);
    __builtin_amdgcn_s_barrier();
    if (i + 3 < nt) STAGE(bi, (i + 3) * 32);
#pragma unroll
    for (int mi = 0; mi < 4; ++mi)
#pragma unroll
      for (int ni = 0; ni < 4; ++ni)
        acc[mi][ni] = __builtin_amdgcn_mfma_f32_16x16x32_bf16(af[mi], bfv[ni], acc[mi][ni], 0, 0, 0);
  }

#pragma unroll
  for (int mi = 0; mi < 4; ++mi)
#pragma unroll
    for (int ni = 0; ni < 4; ++ni) {
      const int row0 = rowA + wr * 64 + mi * 16 + 4 * lg;
      const int col = rowB + wc * 64 + ni * 16 + lr;
#pragma unroll
      for (int r = 0; r < 4; ++r)
        store_elem(C, (size_t)(row0 + r) * N + col, acc[mi][ni][r] * alpha);
    }
}

// ---------------- fused GQA flash attention (swapped QK^T, round-6 body) ----
// qk: [4096][2560] bf16, PRE-SCALED by sqrt(0.125*log2e) on both Q and K parts.
// vt: [512][4096] bf16 (row = g*64+d, col = b*2048+s)
// ctx: [4096][2048] bf16 out
// Block = 128 q-rows (4 waves x 32 rows), KV tile = 64, 2-deep counted-vmcnt dbuf.
// 1D grid of 1024 with XCD-contiguous remap: each XCD owns 8 complete heads,
// so its K/V slabs stay resident in its private L2.
__global__ __launch_bounds__(256, 3) void gqa_attn(const bf16* __restrict__ qk,
                                                   const bf16* __restrict__ vt,
                                                   bf16* __restrict__ ctx) {
  const int t = threadIdx.x, w = t >> 6, lane = t & 63, lg = lane >> 4, lr = lane & 15;
  // bijective remap: flat = xcd + 8*idx  ->  wg = xcd*128 + idx
  const int flat = blockIdx.x;
  const int wg = (flat & 7) * 128 + (flat >> 3);
  const int head = wg >> 4;                 // 0..63
  const int qb = (wg & 15) * 128;           // 16 q-blocks of 128 rows
  const int b = head >> 5, h = head & 31, g = h >> 2;
  const size_t LD = NQK;
  const bf16* Qp = qk + (size_t)b * SS * LD + h * 64;
  const bf16* Kp = qk + (size_t)b * SS * LD + 2048 + g * 64;
  const bf16* Vt = vt + (size_t)(g * 64) * ROWS + b * SS;

  __shared__ __align__(16) bf16 sK[2][64 * 64];      // [key][d], slot-swizzled, dbuf
  __shared__ __align__(16) bf16 sV[2][64 * 64];      // [d][key], slot-swizzled, dbuf
  __shared__ __align__(16) bf16 sP[4][32 * 72];      // per-wave P (32 q-rows), stride 72

  // Q B-fragments (Q^T as B-operand): lane holds q=lr, d = 8*lg+j.
  bf16x8 qf[2][2];
#pragma unroll
  for (int mi = 0; mi < 2; ++mi) {
    const bf16* qrow = Qp + (size_t)(qb + w * 32 + mi * 16 + lr) * LD;
    qf[mi][0] = *(const bf16x8*)(qrow + lg * 8);
    qf[mi][1] = *(const bf16x8*)(qrow + 32 + lg * 8);
  }
  asm volatile("s_waitcnt vmcnt(0)" ::: "memory");   // deterministic vmcnt counting

  float m_run[2], l_part[2];                          // per-lane: q = lr (per mi)
  f32x4 o[2][4];
#pragma unroll
  for (int mi = 0; mi < 2; ++mi) {
    m_run[mi] = -3.0e38f;
    l_part[mi] = 0.0f;
#pragma unroll
    for (int dg = 0; dg < 4; ++dg) o[mi][dg] = (f32x4){0.f, 0.f, 0.f, 0.f};
  }

  auto STAGE = [&](int bi, int kt) {                 // 4 gload_lds / lane
#pragma unroll
    for (int i = 0; i < 2; ++i) {
      const int c = i * 256 + t;           // 16B chunk, 8 chunks/row
      const int r = c >> 3, slot = c & 7;
      const int ck = slot ^ (r & 7);
      gload_lds16(Kp + (size_t)(kt * 64 + r) * LD + ck * 8, &sK[bi][c * 8]);
      gload_lds16(Vt + (size_t)r * ROWS + kt * 64 + ck * 8, &sV[bi][c * 8]);
    }
  };

  const int NT = SS / 64;
  STAGE(0, 0);
  int cur = 0;

  for (int kt = 0; kt < NT; ++kt) {
    if (kt + 1 < NT) {
      STAGE(cur ^ 1, kt + 1);
      asm volatile("s_waitcnt vmcnt(4)" ::: "memory");
    } else {
      asm volatile("s_waitcnt vmcnt(0)" ::: "memory");
    }
    __builtin_amdgcn_s_barrier();

    // S^T = K Q^T  (s[mi][cg][r] = S[q = lr][k = cg*16 + 4*lg + r])
    f32x4 s[2][4];
    __builtin_amdgcn_s_setprio(1);
#pragma unroll
    for (int cg = 0; cg < 4; ++cg) {
      const int kr = cg * 16 + lr;
      bf16x8 kf0 = *(const bf16x8*)&sK[cur][kr * 64 + ((lg) ^ (kr & 7)) * 8];
      bf16x8 kf1 = *(const bf16x8*)&sK[cur][kr * 64 + ((lg + 4) ^ (kr & 7)) * 8];
#pragma unroll
      for (int mi = 0; mi < 2; ++mi) {
        f32x4 z = {0.f, 0.f, 0.f, 0.f};
        z = __builtin_amdgcn_mfma_f32_16x16x32_bf16(kf0, qf[mi][0], z, 0, 0, 0);
        z = __builtin_amdgcn_mfma_f32_16x16x32_bf16(kf1, qf[mi][1], z, 0, 0, 0);
        s[mi][cg] = z;
      }
    }
    __builtin_amdgcn_s_setprio(0);

    // T13 defer-max: lane-local max over this lane's 16 k-values (its q-row slice)
    float pm[2];
    bool ok = true;
#pragma unroll
    for (int mi = 0; mi < 2; ++mi) {
      float m0 = fmaxf(fmaxf(s[mi][0][0], s[mi][0][1]), fmaxf(s[mi][0][2], s[mi][0][3]));
      float m1 = fmaxf(fmaxf(s[mi][1][0], s[mi][1][1]), fmaxf(s[mi][1][2], s[mi][1][3]));
      float m2 = fmaxf(fmaxf(s[mi][2][0], s[mi][2][1]), fmaxf(s[mi][2][2], s[mi][2][3]));
      float m3 = fmaxf(fmaxf(s[mi][3][0], s[mi][3][1]), fmaxf(s[mi][3][2], s[mi][3][3]));
      pm[mi] = fmaxf(fmaxf(m0, m1), fmaxf(m2, m3));
      ok = ok && (pm[mi] <= m_run[mi] + 8.f);
    }
    if (!__all(ok)) {
#pragma unroll
      for (int mi = 0; mi < 2; ++mi) {
        float m = pm[mi];
        m = fmaxf(m, __shfl_xor(m, 16));   // reduce across the 4 lg-groups
        m = fmaxf(m, __shfl_xor(m, 32));
        const float mn = fmaxf(m_run[mi], m);
        const float corr = __builtin_amdgcn_exp2f(m_run[mi] - mn);
        m_run[mi] = mn;
        l_part[mi] *= corr;
        // O rows live at q_local = 4*lg + r — fetch corr from the lane owning that q
#pragma unroll
        for (int r = 0; r < 4; ++r) {
          const float co = __shfl(corr, 20 * lg + r);
#pragma unroll
          for (int dg = 0; dg < 4; ++dg) o[mi][dg][r] *= co;
        }
      }
    }

    // P = exp2(s - m): lane-local q-row; pack pairs (k-consecutive) -> b64 writes
    bf16* sPw = sP[w];
#pragma unroll
    for (int mi = 0; mi < 2; ++mi) {
#pragma unroll
      for (int cg = 0; cg < 4; ++cg) {
        float p0 = __builtin_amdgcn_exp2f(s[mi][cg][0] - m_run[mi]);
        float p1 = __builtin_amdgcn_exp2f(s[mi][cg][1] - m_run[mi]);
        float p2 = __builtin_amdgcn_exp2f(s[mi][cg][2] - m_run[mi]);
        float p3 = __builtin_amdgcn_exp2f(s[mi][cg][3] - m_run[mi]);
        l_part[mi] += (p0 + p1) + (p2 + p3);
        uint2 pk;
        pk.x = cvt_pk_bf16(p0, p1);
        pk.y = cvt_pk_bf16(p2, p3);
        *(uint2*)&sPw[(mi * 16 + lr) * 72 + cg * 16 + 4 * lg] = pk;
      }
    }

    // O += P @ V  (A = P [16 q][64 k], B = V [64 k][16 d])
#pragma unroll
    for (int kc = 0; kc < 2; ++kc) {
      bf16x8 pf[2];
#pragma unroll
      for (int mi = 0; mi < 2; ++mi)
        pf[mi] = *(const bf16x8*)&sPw[(mi * 16 + lr) * 72 + kc * 32 + lg * 8];
      __builtin_amdgcn_s_setprio(1);
#pragma unroll
      for (int dg = 0; dg < 4; ++dg) {
        const int vr = dg * 16 + lr;
        bf16x8 vf = *(const bf16x8*)&sV[cur][vr * 64 + ((kc * 4 + lg) ^ (vr & 7)) * 8];
#pragma unroll
        for (int mi = 0; mi < 2; ++mi)
          o[mi][dg] = __builtin_amdgcn_mfma_f32_16x16x32_bf16(pf[mi], vf, o[mi][dg], 0, 0, 0);
      }
      __builtin_amdgcn_s_setprio(0);
    }

    asm volatile("s_waitcnt lgkmcnt(0)" ::: "memory");
    __builtin_amdgcn_sched_barrier(0);
    __builtin_amdgcn_s_barrier();
    cur ^= 1;
  }

  // final l: sum across lg-groups (q = lr), then hop to O layout (q = 4*lg + r)
#pragma unroll
  for (int mi = 0; mi < 2; ++mi) {
    float l = l_part[mi];
    l += __shfl_xor(l, 16);
    l += __shfl_xor(l, 32);
    const int orow0 = b * SS + qb + w * 32 + mi * 16 + 4 * lg;
#pragma unroll
    for (int r = 0; r < 4; ++r) {
      const float lo = __shfl(l, 20 * lg + r);
      const float inv = 1.0f / lo;
      const int row = orow0 + r;
#pragma unroll
      for (int dg = 0; dg < 4; ++dg) {
        const int col = h * 64 + dg * 16 + lr;
        ctx[(size_t)row * DM + col] = __float2bfloat16(o[mi][dg][r] * inv);
      }
    }
  }
}

// ---------------- launch ----------------
extern "C" void kernel_launch(void* const* d_in, const int* in_sizes, int n_in,
                              void* d_out, int out_size, void* d_ws, size_t ws_size,
                              hipStream_t stream) {
  const float* x   = (const float*)d_in[0];
  const float* W_q = (const float*)d_in[1];
  const float* W_k = (const float*)d_in[2];
  const float* W_v = (const float*)d_in[3];
  const float* W_o = (const float*)d_in[4];
  float* out = (float*)d_out;

  char* ws = (char*)d_ws;
  bf16* xb    = (bf16*)ws; ws += (size_t)ROWS * DM * 2;
  bf16* wqk   = (bf16*)ws; ws += (size_t)NQK * DM * 2;
  bf16* wv    = (bf16*)ws; ws += (size_t)(NG * DH) * DM * 2;
  bf16* wo    = (bf16*)ws; ws += (size_t)DM * DM * 2;
  bf16* qkbuf = (bf16*)ws; ws += (size_t)ROWS * NQK * 2;
  bf16* vtb   = (bf16*)ws; ws += (size_t)(NG * DH) * ROWS * 2;
  bf16* ctx   = (bf16*)ws; ws += (size_t)ROWS * DM * 2;

  // one fused convert: 4,718,592 float4 chunks / 256 = 18432 blocks
  cvt_all<<<18432, 256, 0, stream>>>(x, W_q, W_k, W_v, W_o, xb, wqk, wv, wo);

  // QK projection with exp2-softmax scale folded into BOTH Q and K columns
  gemm_bt<bf16><<<dim3(NQK / 128, ROWS / 128), 256, 0, stream>>>(xb, wqk, qkbuf, ROWS, NQK, DM, ALPHA_QK);
  // V projection, transposed: vtb[512][4096] = wv @ xb^T
  gemm_bt<bf16><<<dim3(ROWS / 128, (NG * DH) / 128), 256, 0, stream>>>(wv, xb, vtb, NG * DH, ROWS, DM, 1.0f);
  // attention: 1024 blocks, XCD-remapped inside the kernel
  gqa_attn<<<1024, 256, 0, stream>>>(qkbuf, vtb, ctx);
  // output projection: out[4096][2048] f32 = ctx @ wo^T
  gemm_bt<float><<<dim3(DM / 128, ROWS / 128), 256, 0, stream>>>(ctx, wo, out, ROWS, DM, DM, 1.0f);
}